// Round 7
// baseline (435.497 us; speedup 1.0000x reference)
//
#include <hip/hip_runtime.h>
#include <math.h>

#define LTOK 2304
#define CDIM 768
#define NHEAD 12
#define HDIM 64
#define HS 48

static constexpr float ATT_SCALE = 0.125f;  // 64^-0.5

typedef short s16x8 __attribute__((ext_vector_type(8)));   // 8 bf16 bits (4 VGPRs)
typedef float f32x4 __attribute__((ext_vector_type(4)));

__device__ __forceinline__ unsigned short f2b(float f) {
  __bf16 b = (__bf16)f;   // RNE
  return __builtin_bit_cast(unsigned short, b);
}
__device__ __forceinline__ float b2f(unsigned short u) {
  unsigned int x = ((unsigned int)u) << 16;
  return __builtin_bit_cast(float, x);
}

__device__ __forceinline__ void gld_lds16(void* lds, const void* g) {
  __builtin_amdgcn_global_load_lds(
      (const __attribute__((address_space(1))) unsigned int*)g,
      (__attribute__((address_space(3))) unsigned int*)lds, 16, 0, 0);
}

// ---------------- fp32 -> bf16 convert (n % 8 == 0) ----------------
__global__ __launch_bounds__(256) void f2b_kernel(const float* __restrict__ in,
                                                  unsigned short* __restrict__ out, int n) {
  const int i = (blockIdx.x * 256 + threadIdx.x) * 8;
  if (i + 8 > n) return;
  float4 v0 = *(const float4*)(in + i);
  float4 v1 = *(const float4*)(in + i + 4);
  alignas(16) unsigned short o[8] = {f2b(v0.x), f2b(v0.y), f2b(v0.z), f2b(v0.w),
                                     f2b(v1.x), f2b(v1.y), f2b(v1.z), f2b(v1.w)};
  *(uint4*)(out + i) = *(const uint4*)o;
}

// ---------------- LayerNorm: fp32 in, bf16 out ----------------
__global__ __launch_bounds__(256) void ln_kernel(const float* __restrict__ x,
                                                 const float* __restrict__ w,
                                                 const float* __restrict__ b,
                                                 unsigned short* __restrict__ out) {
  const int row = blockIdx.x;
  const int t = threadIdx.x;
  const float* xr = x + (size_t)row * CDIM;
  float v0 = xr[t], v1 = xr[t + 256], v2 = xr[t + 512];
  float s = v0 + v1 + v2;
  float ss = v0 * v0 + v1 * v1 + v2 * v2;
#pragma unroll
  for (int off = 32; off > 0; off >>= 1) {
    s += __shfl_down(s, off, 64);
    ss += __shfl_down(ss, off, 64);
  }
  __shared__ float rs[4], rss[4];
  if ((t & 63) == 0) { rs[t >> 6] = s; rss[t >> 6] = ss; }
  __syncthreads();
  float S = rs[0] + rs[1] + rs[2] + rs[3];
  float SS = rss[0] + rss[1] + rss[2] + rss[3];
  const float inv_c = 1.0f / (float)CDIM;
  float mu = S * inv_c;
  float var = SS * inv_c - mu * mu;
  float inv = rsqrtf(var + 1e-5f);
  unsigned short* orow = out + (size_t)row * CDIM;
  orow[t]       = f2b((v0 - mu) * inv * w[t]       + b[t]);
  orow[t + 256] = f2b((v1 - mu) * inv * w[t + 256] + b[t + 256]);
  orow[t + 512] = f2b((v2 - mu) * inv * w[t + 512] + b[t + 512]);
}

// ---------------- bf16 MFMA GEMM (m97 structure) ----------------
template <bool GELU, bool RES, bool OUTBF>
__global__ __launch_bounds__(256) void mfma_gemm(const unsigned short* __restrict__ A,
                                                 const unsigned short* __restrict__ B,
                                                 const float* __restrict__ bias,
                                                 const float* __restrict__ res,
                                                 void* __restrict__ Cout,
                                                 int M, int N, int K) {
  __shared__ unsigned short As[128 * 32];
  __shared__ unsigned short Bs[128 * 32];
  const int t = threadIdx.x;
  const int lane = t & 63;
  const int w = t >> 6;
  const int wm = w >> 1, wn = w & 1;
  const int bm = blockIdx.y * 128, bn = blockIdx.x * 128;

  f32x4 acc[4][4] = {};

  const int c0 = 2 * w, c1 = 2 * w + 1;
  const int srow = lane >> 2;
  const int skof = (lane & 3) * 8;
  const unsigned short* Abase = A + (size_t)bm * K + skof;
  const unsigned short* Bbase = B + (size_t)bn * K + skof;
  const int lr = lane & 15, lk = (lane >> 4) * 8, lg = lane >> 4;

  for (int k0 = 0; k0 < K; k0 += 32) {
    gld_lds16(As + c0 * 512, Abase + (size_t)(c0 * 16 + srow) * K + k0);
    gld_lds16(As + c1 * 512, Abase + (size_t)(c1 * 16 + srow) * K + k0);
    gld_lds16(Bs + c0 * 512, Bbase + (size_t)(c0 * 16 + srow) * K + k0);
    gld_lds16(Bs + c1 * 512, Bbase + (size_t)(c1 * 16 + srow) * K + k0);
    __syncthreads();
    s16x8 a[4], b[4];
#pragma unroll
    for (int m = 0; m < 4; ++m)
      a[m] = *(const s16x8*)&As[(wm * 64 + m * 16 + lr) * 32 + lk];
#pragma unroll
    for (int n = 0; n < 4; ++n)
      b[n] = *(const s16x8*)&Bs[(wn * 64 + n * 16 + lr) * 32 + lk];
#pragma unroll
    for (int m = 0; m < 4; ++m)
#pragma unroll
      for (int n = 0; n < 4; ++n)
        acc[m][n] = __builtin_amdgcn_mfma_f32_16x16x32_bf16(a[m], b[n], acc[m][n], 0, 0, 0);
    __syncthreads();
  }

#pragma unroll
  for (int n = 0; n < 4; ++n) {
    const int col = bn + wn * 64 + n * 16 + lr;
    const float bc = bias[col];
#pragma unroll
    for (int m = 0; m < 4; ++m) {
#pragma unroll
      for (int j = 0; j < 4; ++j) {
        const int row = bm + wm * 64 + m * 16 + lg * 4 + j;
        float v = acc[m][n][j] + bc;
        if (GELU) v = 0.5f * v * (1.0f + erff(v * 0.70710678118654752f));
        if (RES) v += res[(size_t)row * N + col];
        if (OUTBF) ((unsigned short*)Cout)[(size_t)row * N + col] = f2b(v);
        else       ((float*)Cout)[(size_t)row * N + col] = v;
      }
    }
  }
}

// ---------------- RoPE cos/sin tables: [L][32] ----------------
__global__ __launch_bounds__(256) void rope_cs_kernel(float* __restrict__ cs,
                                                      float* __restrict__ sn) {
  const int idx = blockIdx.x * 256 + threadIdx.x;  // < 2304*32
  const int l = idx >> 5;
  const int i = idx & 31;
  const int j = i & 15;
  const float f = __expf(-(float)j * 0.57564627324851142f);
  const float coord = (i < 16) ? (float)(l % HS) : (float)(l / HS);
  const float ang = coord * f;
  cs[idx] = cosf(ang);
  sn[idx] = sinf(ang);
}

// ---------------- prep: fp32 qkv -> Qb,Kb [NH][L][64] (RoPE) + Vb [NH][64][L] -------
// grid (36, 12), 256 threads
__global__ __launch_bounds__(256) void prep_kernel(const float* __restrict__ qkv,
                                                   const float* __restrict__ cs,
                                                   const float* __restrict__ sn,
                                                   unsigned short* __restrict__ Qb,
                                                   unsigned short* __restrict__ Kb,
                                                   unsigned short* __restrict__ Vb) {
  __shared__ unsigned short Vs[64 * 72];
  const int t = threadIdx.x;
  const int l0 = blockIdx.x * 64, n = blockIdx.y;
  const int r = t >> 2, c = t & 3;
  const int l = l0 + r;
  const float* base = qkv + (size_t)l * (3 * CDIM) + n * HDIM + c * 16;
#pragma unroll
  for (int pq = 0; pq < 2; ++pq) {
    const float* src = base + pq * CDIM;
    alignas(16) unsigned short o[16];
#pragma unroll
    for (int i = 0; i < 4; ++i) {
      float4 v = *(const float4*)(src + i * 4);
      const int pr = c * 8 + i * 2;
      const float c0 = cs[l * 32 + pr],     s0 = sn[l * 32 + pr];
      const float c1 = cs[l * 32 + pr + 1], s1 = sn[l * 32 + pr + 1];
      o[i * 4 + 0] = f2b(v.x * c0 - v.y * s0);
      o[i * 4 + 1] = f2b(v.x * s0 + v.y * c0);
      o[i * 4 + 2] = f2b(v.z * c1 - v.w * s1);
      o[i * 4 + 3] = f2b(v.z * s1 + v.w * c1);
    }
    unsigned short* dst = (pq ? Kb : Qb) + ((size_t)n * LTOK + l) * HDIM + c * 16;
    *(uint4*)dst = *(const uint4*)o;
    *(uint4*)(dst + 8) = *(const uint4*)(o + 8);
  }
  // V transpose via LDS (coalesced in and out)
  {
    const float* vsrc = base + 2 * CDIM;
    alignas(16) unsigned short vo[16];
#pragma unroll
    for (int i = 0; i < 4; ++i) {
      float4 v = *(const float4*)(vsrc + i * 4);
      vo[i * 4 + 0] = f2b(v.x); vo[i * 4 + 1] = f2b(v.y);
      vo[i * 4 + 2] = f2b(v.z); vo[i * 4 + 3] = f2b(v.w);
    }
    *(uint4*)&Vs[r * 72 + c * 16] = *(const uint4*)vo;
    *(uint4*)&Vs[r * 72 + c * 16 + 8] = *(const uint4*)(vo + 8);
  }
  __syncthreads();
  {
    const int d = t >> 2, kc = (t & 3) * 16;
    alignas(16) unsigned short o[16];
#pragma unroll
    for (int i = 0; i < 16; ++i) o[i] = Vs[(kc + i) * 72 + d];
    unsigned short* dst = Vb + ((size_t)n * HDIM + d) * LTOK + l0 + kc;
    *(uint4*)dst = *(const uint4*)o;
    *(uint4*)(dst + 8) = *(const uint4*)(o + 8);
  }
}

// ---------------- MFMA flash attention, KVB=48, double-buffered K/V ----------------
// grid = 432 linear (XCD-swizzled), 256 threads = 4 waves x 16 q-rows.
// One KV step = { stage next tile ; QK^T MFMA ; softmax ; PV MFMA ; barrier }.
// STEP is a macro (NOT a lambda): R6's [&]-lambda put accO/bwreg behind a
// closure reference -> scratch spill (VGPR 256, 141MB scratch writes).
#define ATTN_STEP(Kc, Vc, Kn, Vn, kt, ktn, STAGE)                                        \
  do {                                                                                   \
    if (STAGE) {                                                                         \
      gld_lds16((Kn) + w * 512, Khead + (size_t)((ktn) * 48 + w * 8 + rowb) * HDIM + srcc * 8); \
      if (w < 2)                                                                         \
        gld_lds16((Kn) + (4 + w) * 512,                                                  \
                  Khead + (size_t)((ktn) * 48 + (4 + w) * 8 + rowb) * HDIM + srcc * 8);  \
      gld_lds16((Vn) + w * 512, Vhead + (size_t)vr0 * LTOK + (ktn) * 48 + vc0);          \
      if (w >= 2)                                                                        \
        gld_lds16((Vn) + cw * 512, Vhead + (size_t)vr1 * LTOK + (ktn) * 48 + vc1);       \
    }                                                                                    \
    f32x4 st0 = {}, st1 = {}, st2 = {};                                                  \
    __builtin_amdgcn_s_setprio(1);                                                       \
    {                                                                                    \
      s16x8 kf0 = *(const s16x8*)&(Kc)[(p) * 64 + sw0 * 8];                              \
      s16x8 kf1 = *(const s16x8*)&(Kc)[(p) * 64 + sw1 * 8];                              \
      st0 = __builtin_amdgcn_mfma_f32_16x16x32_bf16(kf0, qf0, st0, 0, 0, 0);             \
      st0 = __builtin_amdgcn_mfma_f32_16x16x32_bf16(kf1, qf1, st0, 0, 0, 0);             \
      kf0 = *(const s16x8*)&(Kc)[(16 + p) * 64 + sw0 * 8];                               \
      kf1 = *(const s16x8*)&(Kc)[(16 + p) * 64 + sw1 * 8];                               \
      st1 = __builtin_amdgcn_mfma_f32_16x16x32_bf16(kf0, qf0, st1, 0, 0, 0);             \
      st1 = __builtin_amdgcn_mfma_f32_16x16x32_bf16(kf1, qf1, st1, 0, 0, 0);             \
      kf0 = *(const s16x8*)&(Kc)[(32 + p) * 64 + sw0 * 8];                               \
      kf1 = *(const s16x8*)&(Kc)[(32 + p) * 64 + sw1 * 8];                               \
      st2 = __builtin_amdgcn_mfma_f32_16x16x32_bf16(kf0, qf0, st2, 0, 0, 0);             \
      st2 = __builtin_amdgcn_mfma_f32_16x16x32_bf16(kf1, qf1, st2, 0, 0, 0);             \
    }                                                                                    \
    __builtin_amdgcn_s_setprio(0);                                                       \
    const float bhv = bh_t[(kt) * 64 + w * 16 + p];                                      \
    float sv[12];                                                                        \
    _Pragma("unroll") for (int jj = 0; jj < 4; ++jj) {                                   \
      sv[jj]     = st0[jj] * ATT_SCALE + bhv + bwreg[jj];                                \
      sv[4 + jj] = st1[jj] * ATT_SCALE + bhv + bwreg[4 + jj];                            \
      sv[8 + jj] = st2[jj] * ATT_SCALE + bhv + bwreg[8 + jj];                            \
    }                                                                                    \
    float tm = sv[0];                                                                    \
    _Pragma("unroll") for (int i = 1; i < 12; ++i) tm = fmaxf(tm, sv[i]);                \
    tm = fmaxf(tm, __shfl_xor(tm, 16, 64));                                              \
    tm = fmaxf(tm, __shfl_xor(tm, 32, 64));                                              \
    const float mn = fmaxf(m, tm);                                                       \
    const float alpha = __expf(m - mn);                                                  \
    m = mn;                                                                              \
    float pv[12], ps = 0.f;                                                              \
    _Pragma("unroll") for (int i = 0; i < 12; ++i) { pv[i] = __expf(sv[i] - mn); ps += pv[i]; } \
    ps += __shfl_xor(ps, 16, 64);                                                        \
    ps += __shfl_xor(ps, 32, 64);                                                        \
    lsum = lsum * alpha + ps;                                                            \
    accO0 *= alpha; accO1 *= alpha; accO2 *= alpha; accO3 *= alpha;                      \
    _Pragma("unroll") for (int mb = 0; mb < 3; ++mb) {                                   \
      unsigned int lo = (unsigned int)f2b(pv[mb * 4 + 0]) | ((unsigned int)f2b(pv[mb * 4 + 1]) << 16); \
      unsigned int hi = (unsigned int)f2b(pv[mb * 4 + 2]) | ((unsigned int)f2b(pv[mb * 4 + 3]) << 16); \
      uint2 val = {lo, hi};                                                              \
      *(uint2*)&Pw[p * 72 + 16 * mb + 4 * g] = val;                                      \
    }                                                                                    \
    const s16x8 pf0 = *(const s16x8*)&Pw[p * 72 + g * 8];                                \
    const s16x8 pf1 = *(const s16x8*)&Pw[p * 72 + 32 + g * 8];                           \
    __builtin_amdgcn_s_setprio(1);                                                       \
    {                                                                                    \
      s16x8 vf0 = *(const s16x8*)&(Vc)[(p) * 48 + g * 8];                                \
      s16x8 vf1 = *(const s16x8*)&(Vc)[(p) * 48 + 32 + g * 8];                           \
      accO0 = __builtin_amdgcn_mfma_f32_16x16x32_bf16(vf0, pf0, accO0, 0, 0, 0);         \
      accO0 = __builtin_amdgcn_mfma_f32_16x16x32_bf16(vf1, pf1, accO0, 0, 0, 0);         \
      vf0 = *(const s16x8*)&(Vc)[(16 + p) * 48 + g * 8];                                 \
      vf1 = *(const s16x8*)&(Vc)[(16 + p) * 48 + 32 + g * 8];                            \
      accO1 = __builtin_amdgcn_mfma_f32_16x16x32_bf16(vf0, pf0, accO1, 0, 0, 0);         \
      accO1 = __builtin_amdgcn_mfma_f32_16x16x32_bf16(vf1, pf1, accO1, 0, 0, 0);         \
      vf0 = *(const s16x8*)&(Vc)[(32 + p) * 48 + g * 8];                                 \
      vf1 = *(const s16x8*)&(Vc)[(32 + p) * 48 + 32 + g * 8];                            \
      accO2 = __builtin_amdgcn_mfma_f32_16x16x32_bf16(vf0, pf0, accO2, 0, 0, 0);         \
      accO2 = __builtin_amdgcn_mfma_f32_16x16x32_bf16(vf1, pf1, accO2, 0, 0, 0);         \
      vf0 = *(const s16x8*)&(Vc)[(48 + p) * 48 + g * 8];                                 \
      vf1 = *(const s16x8*)&(Vc)[(48 + p) * 48 + 32 + g * 8];                            \
      accO3 = __builtin_amdgcn_mfma_f32_16x16x32_bf16(vf0, pf0, accO3, 0, 0, 0);         \
      accO3 = __builtin_amdgcn_mfma_f32_16x16x32_bf16(vf1, pf1, accO3, 0, 0, 0);         \
    }                                                                                    \
    __builtin_amdgcn_s_setprio(0);                                                       \
    __syncthreads();                                                                     \
  } while (0)

__global__ __launch_bounds__(256, 3) void attn_mfma(const unsigned short* __restrict__ Qb,
                                                    const unsigned short* __restrict__ Kb,
                                                    const unsigned short* __restrict__ Vb,
                                                    const float* __restrict__ relh,
                                                    const float* __restrict__ relw,
                                                    unsigned short* __restrict__ out) {
  __shared__ __align__(16) unsigned char smem[46208];
  unsigned short* const K0 = (unsigned short*)(smem);
  unsigned short* const V0 = (unsigned short*)(smem + 6144);
  unsigned short* const K1 = (unsigned short*)(smem + 12352);
  unsigned short* const V1 = (unsigned short*)(smem + 18496);
  unsigned short* const P_lds = (unsigned short*)(smem + 24704);
  float* const bh_t = (float*)(smem + 33920);
  unsigned short* const Q_s = (unsigned short*)(smem + 12352);  // overlays K1/V1

  const int t = threadIdx.x;
  const int lane = t & 63, w = t >> 6;
  const int p = lane & 15, g = lane >> 4;
  const int bid = blockIdx.x;
  const int swz = (bid & 7) * 54 + (bid >> 3);  // 432 = 8 XCDs * 54
  const int l0 = (swz % 36) * 64, n = swz / 36;

  const unsigned short* Khead = Kb + (size_t)n * LTOK * HDIM;
  const unsigned short* Vhead = Vb + (size_t)n * HDIM * LTOK;

  // ---- prologue ----
  {
    const int r = t >> 2, c = t & 3;
    const unsigned short* src = Qb + ((size_t)n * LTOK + l0 + r) * HDIM + c * 16;
    uint4 v0 = *(const uint4*)src;
    uint4 v1 = *(const uint4*)(src + 8);
    *(uint4*)&Q_s[r * 72 + c * 16] = v0;
    *(uint4*)&Q_s[r * 72 + c * 16 + 8] = v1;
  }
  __syncthreads();

  const int rowb = lane >> 3;
  const int srcc = (lane & 7) ^ rowb;
  const int vBb0 = w * 1024 + lane * 16;
  const int vr0 = vBb0 / 96, vc0 = (vBb0 % 96) >> 1;
  const int cw = 2 + w;  // Vt chunks 4,5 for w=2,3
  const int vBb1 = cw * 1024 + lane * 16;
  const int vr1 = vBb1 / 96, vc1 = (vBb1 % 96) >> 1;
  {
    gld_lds16(K0 + w * 512, Khead + (size_t)(w * 8 + rowb) * HDIM + srcc * 8);
    if (w < 2)
      gld_lds16(K0 + (4 + w) * 512, Khead + (size_t)((4 + w) * 8 + rowb) * HDIM + srcc * 8);
    gld_lds16(V0 + w * 512, Vhead + (size_t)vr0 * LTOK + vc0);
    if (w >= 2)
      gld_lds16(V0 + cw * 512, Vhead + (size_t)vr1 * LTOK + vc1);
  }

  const s16x8 qf0 = *(const s16x8*)&Q_s[(w * 16 + p) * 72 + g * 8];
  const s16x8 qf1 = *(const s16x8*)&Q_s[(w * 16 + p) * 72 + 32 + g * 8];

  const int qh_lane = (l0 + lane) / 48;
#pragma unroll
  for (int i = 0; i < 12; ++i) {
    const int kt = w + 4 * i;
    const float* rrow = relh + (size_t)(qh_lane - kt + 47) * HDIM;
    float acc = 0.f;
#pragma unroll
    for (int c8 = 0; c8 < 8; ++c8) {
      s16x8 qv = *(const s16x8*)&Q_s[lane * 72 + c8 * 8];
      float4 ra = *(const float4*)&rrow[c8 * 8];
      float4 rb = *(const float4*)&rrow[c8 * 8 + 4];
      acc += b2f((unsigned short)qv[0]) * ra.x + b2f((unsigned short)qv[1]) * ra.y +
             b2f((unsigned short)qv[2]) * ra.z + b2f((unsigned short)qv[3]) * ra.w +
             b2f((unsigned short)qv[4]) * rb.x + b2f((unsigned short)qv[5]) * rb.y +
             b2f((unsigned short)qv[6]) * rb.z + b2f((unsigned short)qv[7]) * rb.w;
    }
    bh_t[kt * 64 + lane] = acc;
  }

  float bwreg[12];
  {
    const int qrow = w * 16 + p;
    const int qw_lane = (l0 + qrow) % 48;
#pragma unroll
    for (int mb = 0; mb < 3; ++mb)
#pragma unroll
      for (int jj = 0; jj < 4; ++jj) {
        const int j = 16 * mb + 4 * g + jj;
        const float* rrow = relw + (size_t)(qw_lane - j + 47) * HDIM;
        float acc = 0.f;
#pragma unroll
        for (int c8 = 0; c8 < 8; ++c8) {
          s16x8 qv = *(const s16x8*)&Q_s[qrow * 72 + c8 * 8];
          float4 ra = *(const float4*)&rrow[c8 * 8];
          float4 rb = *(const float4*)&rrow[c8 * 8 + 4];
          acc += b2f((unsigned short)qv[0]) * ra.x + b2f((unsigned short)qv[1]) * ra.y +
                 b2f((unsigned short)qv[2]) * ra.z + b2f((unsigned short)qv[3]) * ra.w +
                 b2f((unsigned short)qv[4]) * rb.x + b2f((unsigned short)qv[5]) * rb.y +
                 b2f((unsigned short)qv[6]) * rb.z + b2f((unsigned short)qv[7]) * rb.w;
        }
        bwreg[mb * 4 + jj] = acc;
      }
  }

  // one-time zero pads: P key range [48,64); Vt tails
  {
    uint2 z = {0u, 0u};
    *(uint2*)&P_lds[w * 16 * 72 + p * 72 + 48 + 4 * g] = z;
    if (t < 16) V0[64 * 48 + t] = 0;
    else if (t < 32) V1[64 * 48 + (t - 16)] = 0;
  }
  __syncthreads();  // drains tile-0 loads; Q_s dead after this point

  float m = -3e38f, lsum = 0.f;
  f32x4 accO0 = {}, accO1 = {}, accO2 = {}, accO3 = {};
  const int sw0 = g ^ (p & 7);
  const int sw1 = (g + 4) ^ (p & 7);
  unsigned short* const Pw = P_lds + w * 16 * 72;

  for (int kt2 = 0; kt2 < 46; kt2 += 2) {
    ATTN_STEP(K0, V0, K1, V1, kt2, kt2 + 1, 1);
    ATTN_STEP(K1, V1, K0, V0, kt2 + 1, kt2 + 2, 1);
  }
  ATTN_STEP(K0, V0, K1, V1, 46, 47, 1);
  ATTN_STEP(K1, V1, K0, V0, 47, 0, 0);

  // epilogue
  const float inv = 1.0f / lsum;
  unsigned short* orow = out + (size_t)(l0 + w * 16 + p) * CDIM + n * HDIM;
#pragma unroll
  for (int db = 0; db < 4; ++db) {
    const f32x4 a = (db == 0) ? accO0 : (db == 1) ? accO1 : (db == 2) ? accO2 : accO3;
    unsigned int lo = (unsigned int)f2b(a[0] * inv) | ((unsigned int)f2b(a[1] * inv) << 16);
    unsigned int hi = (unsigned int)f2b(a[2] * inv) | ((unsigned int)f2b(a[3] * inv) << 16);
    uint2 val = {lo, hi};
    *(uint2*)&orow[16 * db + 4 * g] = val;
  }
}

// ---------------- launch ----------------
extern "C" void kernel_launch(void* const* d_in, const int* in_sizes, int n_in,
                              void* d_out, int out_size, void* d_ws, size_t ws_size,
                              hipStream_t stream) {
  const float* x     = (const float*)d_in[0];
  const float* ln1w  = (const float*)d_in[1];
  const float* ln1b  = (const float*)d_in[2];
  const float* qkvw  = (const float*)d_in[3];
  const float* qkvb  = (const float*)d_in[4];
  const float* relh  = (const float*)d_in[5];
  const float* relw  = (const float*)d_in[6];
  const float* projw = (const float*)d_in[7];
  const float* projb = (const float*)d_in[8];
  const float* ln2w  = (const float*)d_in[9];
  const float* ln2b  = (const float*)d_in[10];
  const float* fc1w  = (const float*)d_in[11];
  const float* fc1b  = (const float*)d_in[12];
  const float* fc2w  = (const float*)d_in[13];
  const float* fc2b  = (const float*)d_in[14];
  float* out = (float*)d_out;
  float* ws = (float*)d_ws;

  float* qkv = ws;                             // L*3C f32
  float* x1  = qkv + (size_t)LTOK * 3 * CDIM;  // L*C f32 (overlaid by Qb/Kb before proj)
  float* cs  = x1 + (size_t)LTOK * CDIM;
  float* sn  = cs + (size_t)LTOK * 32;
  unsigned short* h_bf    = (unsigned short*)(sn + (size_t)LTOK * 32);
  unsigned short* attn_bf = h_bf + (size_t)LTOK * CDIM;
  unsigned short* wq      = attn_bf + (size_t)LTOK * CDIM;
  unsigned short* wproj   = wq + (size_t)3 * CDIM * CDIM;
  unsigned short* wfc1    = wproj + (size_t)CDIM * CDIM;
  unsigned short* wfc2    = wfc1 + (size_t)4 * CDIM * CDIM;
  unsigned short* Qb      = (unsigned short*)x1;   // Qb+Kb fit x1 exactly
  unsigned short* Kb      = Qb + (size_t)NHEAD * LTOK * HDIM;
  unsigned short* Vb      = wq;                    // overlay: wq dead after qkv GEMM
  unsigned short* m1_bf   = (unsigned short*)qkv;  // overlay: qkv dead after prep

  f2b_kernel<<<(3 * CDIM * CDIM / 8 + 255) / 256, 256, 0, stream>>>(qkvw, wq, 3 * CDIM * CDIM);
  f2b_kernel<<<(CDIM * CDIM / 8 + 255) / 256, 256, 0, stream>>>(projw, wproj, CDIM * CDIM);
  f2b_kernel<<<(4 * CDIM * CDIM / 8 + 255) / 256, 256, 0, stream>>>(fc1w, wfc1, 4 * CDIM * CDIM);
  f2b_kernel<<<(4 * CDIM * CDIM / 8 + 255) / 256, 256, 0, stream>>>(fc2w, wfc2, 4 * CDIM * CDIM);

  ln_kernel<<<LTOK, 256, 0, stream>>>(x, ln1w, ln1b, h_bf);
  mfma_gemm<false, false, false><<<dim3(18, 18), 256, 0, stream>>>(
      h_bf, wq, qkvb, nullptr, qkv, LTOK, 3 * CDIM, CDIM);
  rope_cs_kernel<<<288, 256, 0, stream>>>(cs, sn);
  prep_kernel<<<dim3(36, 12), 256, 0, stream>>>(qkv, cs, sn, Qb, Kb, Vb);
  attn_mfma<<<432, 256, 0, stream>>>(Qb, Kb, Vb, relh, relw, attn_bf);
  mfma_gemm<false, true, false><<<dim3(6, 18), 256, 0, stream>>>(
      attn_bf, wproj, projb, x, x1, LTOK, CDIM, CDIM);
  ln_kernel<<<LTOK, 256, 0, stream>>>(x1, ln2w, ln2b, h_bf);
  mfma_gemm<true, false, true><<<dim3(24, 18), 256, 0, stream>>>(
      h_bf, wfc1, fc1b, nullptr, m1_bf, LTOK, 4 * CDIM, CDIM);
  mfma_gemm<false, true, false><<<dim3(6, 18), 256, 0, stream>>>(
      m1_bf, wfc2, fc2b, x1, out, LTOK, CDIM, 4 * CDIM);
}

// Round 8
// 408.766 us; speedup vs baseline: 1.0654x; 1.0654x over previous
//
#include <hip/hip_runtime.h>
#include <math.h>

#define LTOK 2304
#define CDIM 768
#define NHEAD 12
#define HDIM 64
#define HS 48

static constexpr float ATT_SCALE = 0.125f;  // 64^-0.5

typedef short s16x8 __attribute__((ext_vector_type(8)));   // 8 bf16 bits (4 VGPRs)
typedef float f32x4 __attribute__((ext_vector_type(4)));

__device__ __forceinline__ unsigned short f2b(float f) {
  __bf16 b = (__bf16)f;   // RNE
  return __builtin_bit_cast(unsigned short, b);
}
__device__ __forceinline__ float b2f(unsigned short u) {
  unsigned int x = ((unsigned int)u) << 16;
  return __builtin_bit_cast(float, x);
}

__device__ __forceinline__ void gld_lds16(void* lds, const void* g) {
  __builtin_amdgcn_global_load_lds(
      (const __attribute__((address_space(1))) unsigned int*)g,
      (__attribute__((address_space(3))) unsigned int*)lds, 16, 0, 0);
}

// ---------------- fp32 -> bf16 convert (n % 8 == 0) ----------------
__global__ __launch_bounds__(256) void f2b_kernel(const float* __restrict__ in,
                                                  unsigned short* __restrict__ out, int n) {
  const int i = (blockIdx.x * 256 + threadIdx.x) * 8;
  if (i + 8 > n) return;
  float4 v0 = *(const float4*)(in + i);
  float4 v1 = *(const float4*)(in + i + 4);
  alignas(16) unsigned short o[8] = {f2b(v0.x), f2b(v0.y), f2b(v0.z), f2b(v0.w),
                                     f2b(v1.x), f2b(v1.y), f2b(v1.z), f2b(v1.w)};
  *(uint4*)(out + i) = *(const uint4*)o;
}

// ---------------- LayerNorm: fp32 in, bf16 out ----------------
__global__ __launch_bounds__(256) void ln_kernel(const float* __restrict__ x,
                                                 const float* __restrict__ w,
                                                 const float* __restrict__ b,
                                                 unsigned short* __restrict__ out) {
  const int row = blockIdx.x;
  const int t = threadIdx.x;
  const float* xr = x + (size_t)row * CDIM;
  float v0 = xr[t], v1 = xr[t + 256], v2 = xr[t + 512];
  float s = v0 + v1 + v2;
  float ss = v0 * v0 + v1 * v1 + v2 * v2;
#pragma unroll
  for (int off = 32; off > 0; off >>= 1) {
    s += __shfl_down(s, off, 64);
    ss += __shfl_down(ss, off, 64);
  }
  __shared__ float rs[4], rss[4];
  if ((t & 63) == 0) { rs[t >> 6] = s; rss[t >> 6] = ss; }
  __syncthreads();
  float S = rs[0] + rs[1] + rs[2] + rs[3];
  float SS = rss[0] + rss[1] + rss[2] + rss[3];
  const float inv_c = 1.0f / (float)CDIM;
  float mu = S * inv_c;
  float var = SS * inv_c - mu * mu;
  float inv = rsqrtf(var + 1e-5f);
  unsigned short* orow = out + (size_t)row * CDIM;
  orow[t]       = f2b((v0 - mu) * inv * w[t]       + b[t]);
  orow[t + 256] = f2b((v1 - mu) * inv * w[t + 256] + b[t + 256]);
  orow[t + 512] = f2b((v2 - mu) * inv * w[t + 512] + b[t + 512]);
}

// ---------------- bf16 MFMA GEMM (m97 structure) ----------------
template <bool GELU, bool RES, bool OUTBF>
__global__ __launch_bounds__(256) void mfma_gemm(const unsigned short* __restrict__ A,
                                                 const unsigned short* __restrict__ B,
                                                 const float* __restrict__ bias,
                                                 const float* __restrict__ res,
                                                 void* __restrict__ Cout,
                                                 int M, int N, int K) {
  __shared__ unsigned short As[128 * 32];
  __shared__ unsigned short Bs[128 * 32];
  const int t = threadIdx.x;
  const int lane = t & 63;
  const int w = t >> 6;
  const int wm = w >> 1, wn = w & 1;
  const int bm = blockIdx.y * 128, bn = blockIdx.x * 128;

  f32x4 acc[4][4] = {};

  const int c0 = 2 * w, c1 = 2 * w + 1;
  const int srow = lane >> 2;
  const int skof = (lane & 3) * 8;
  const unsigned short* Abase = A + (size_t)bm * K + skof;
  const unsigned short* Bbase = B + (size_t)bn * K + skof;
  const int lr = lane & 15, lk = (lane >> 4) * 8, lg = lane >> 4;

  for (int k0 = 0; k0 < K; k0 += 32) {
    gld_lds16(As + c0 * 512, Abase + (size_t)(c0 * 16 + srow) * K + k0);
    gld_lds16(As + c1 * 512, Abase + (size_t)(c1 * 16 + srow) * K + k0);
    gld_lds16(Bs + c0 * 512, Bbase + (size_t)(c0 * 16 + srow) * K + k0);
    gld_lds16(Bs + c1 * 512, Bbase + (size_t)(c1 * 16 + srow) * K + k0);
    __syncthreads();
    s16x8 a[4], b[4];
#pragma unroll
    for (int m = 0; m < 4; ++m)
      a[m] = *(const s16x8*)&As[(wm * 64 + m * 16 + lr) * 32 + lk];
#pragma unroll
    for (int n = 0; n < 4; ++n)
      b[n] = *(const s16x8*)&Bs[(wn * 64 + n * 16 + lr) * 32 + lk];
#pragma unroll
    for (int m = 0; m < 4; ++m)
#pragma unroll
      for (int n = 0; n < 4; ++n)
        acc[m][n] = __builtin_amdgcn_mfma_f32_16x16x32_bf16(a[m], b[n], acc[m][n], 0, 0, 0);
    __syncthreads();
  }

#pragma unroll
  for (int n = 0; n < 4; ++n) {
    const int col = bn + wn * 64 + n * 16 + lr;
    const float bc = bias[col];
#pragma unroll
    for (int m = 0; m < 4; ++m) {
#pragma unroll
      for (int j = 0; j < 4; ++j) {
        const int row = bm + wm * 64 + m * 16 + lg * 4 + j;
        float v = acc[m][n][j] + bc;
        if (GELU) v = 0.5f * v * (1.0f + erff(v * 0.70710678118654752f));
        if (RES) v += res[(size_t)row * N + col];
        if (OUTBF) ((unsigned short*)Cout)[(size_t)row * N + col] = f2b(v);
        else       ((float*)Cout)[(size_t)row * N + col] = v;
      }
    }
  }
}

// ---------------- RoPE cos/sin tables: [L][32] ----------------
__global__ __launch_bounds__(256) void rope_cs_kernel(float* __restrict__ cs,
                                                      float* __restrict__ sn) {
  const int idx = blockIdx.x * 256 + threadIdx.x;  // < 2304*32
  const int l = idx >> 5;
  const int i = idx & 31;
  const int j = i & 15;
  const float f = __expf(-(float)j * 0.57564627324851142f);
  const float coord = (i < 16) ? (float)(l % HS) : (float)(l / HS);
  const float ang = coord * f;
  cs[idx] = cosf(ang);
  sn[idx] = sinf(ang);
}

// ---------------- prep: fp32 qkv -> Qb,Kb [NH][L][64] (RoPE) + Vb [NH][64][L] -------
// grid (36, 12), 256 threads
__global__ __launch_bounds__(256) void prep_kernel(const float* __restrict__ qkv,
                                                   const float* __restrict__ cs,
                                                   const float* __restrict__ sn,
                                                   unsigned short* __restrict__ Qb,
                                                   unsigned short* __restrict__ Kb,
                                                   unsigned short* __restrict__ Vb) {
  __shared__ unsigned short Vs[64 * 72];
  const int t = threadIdx.x;
  const int l0 = blockIdx.x * 64, n = blockIdx.y;
  const int r = t >> 2, c = t & 3;
  const int l = l0 + r;
  const float* base = qkv + (size_t)l * (3 * CDIM) + n * HDIM + c * 16;
#pragma unroll
  for (int pq = 0; pq < 2; ++pq) {
    const float* src = base + pq * CDIM;
    alignas(16) unsigned short o[16];
#pragma unroll
    for (int i = 0; i < 4; ++i) {
      float4 v = *(const float4*)(src + i * 4);
      const int pr = c * 8 + i * 2;
      const float c0 = cs[l * 32 + pr],     s0 = sn[l * 32 + pr];
      const float c1 = cs[l * 32 + pr + 1], s1 = sn[l * 32 + pr + 1];
      o[i * 4 + 0] = f2b(v.x * c0 - v.y * s0);
      o[i * 4 + 1] = f2b(v.x * s0 + v.y * c0);
      o[i * 4 + 2] = f2b(v.z * c1 - v.w * s1);
      o[i * 4 + 3] = f2b(v.z * s1 + v.w * c1);
    }
    unsigned short* dst = (pq ? Kb : Qb) + ((size_t)n * LTOK + l) * HDIM + c * 16;
    *(uint4*)dst = *(const uint4*)o;
    *(uint4*)(dst + 8) = *(const uint4*)(o + 8);
  }
  // V transpose via LDS (coalesced in and out)
  {
    const float* vsrc = base + 2 * CDIM;
    alignas(16) unsigned short vo[16];
#pragma unroll
    for (int i = 0; i < 4; ++i) {
      float4 v = *(const float4*)(vsrc + i * 4);
      vo[i * 4 + 0] = f2b(v.x); vo[i * 4 + 1] = f2b(v.y);
      vo[i * 4 + 2] = f2b(v.z); vo[i * 4 + 3] = f2b(v.w);
    }
    *(uint4*)&Vs[r * 72 + c * 16] = *(const uint4*)vo;
    *(uint4*)&Vs[r * 72 + c * 16 + 8] = *(const uint4*)(vo + 8);
  }
  __syncthreads();
  {
    const int d = t >> 2, kc = (t & 3) * 16;
    alignas(16) unsigned short o[16];
#pragma unroll
    for (int i = 0; i < 16; ++i) o[i] = Vs[(kc + i) * 72 + d];
    unsigned short* dst = Vb + ((size_t)n * HDIM + d) * LTOK + l0 + kc;
    *(uint4*)dst = *(const uint4*)o;
    *(uint4*)(dst + 8) = *(const uint4*)(o + 8);
  }
}

// ---------------- MFMA flash attention, KVB=48, double-buffered K/V ----------------
// grid (36, 12), 256 threads = 4 waves x 16 q-rows.
// One step = { stage tile kt+1 into Kn/Vn ; QK^T from Kc ; softmax ; PV from Vc ;
//              ONE barrier ; swap }.  Plain loop, single body copy, pointer-swap
// dbuf (R6 lambda / R7 macro-duplication both put sv/pv in scratch: 290MB WRITE).
// LDS map (bytes): K0@0(6144) V0@6144(6176) K1@12352(6144) V1@18496(6176)
//                  P@24704(9216) bh@33920(12288)  total 46208
//                  Q_s overlays K1/V1 @12352 (9216; dead after prologue)
__global__ __launch_bounds__(256) void attn_mfma(const unsigned short* __restrict__ Qb,
                                                 const unsigned short* __restrict__ Kb,
                                                 const unsigned short* __restrict__ Vb,
                                                 const float* __restrict__ relh,
                                                 const float* __restrict__ relw,
                                                 unsigned short* __restrict__ out) {
  __shared__ __align__(16) unsigned char smem[46208];
  unsigned short* const K0 = (unsigned short*)(smem);
  unsigned short* const V0 = (unsigned short*)(smem + 6144);
  unsigned short* const K1 = (unsigned short*)(smem + 12352);
  unsigned short* const V1 = (unsigned short*)(smem + 18496);
  unsigned short* const P_lds = (unsigned short*)(smem + 24704);
  float* const bh_t = (float*)(smem + 33920);
  unsigned short* const Q_s = (unsigned short*)(smem + 12352);  // overlays K1/V1

  const int t = threadIdx.x;
  const int lane = t & 63, w = t >> 6;
  const int p = lane & 15, g = lane >> 4;
  const int l0 = blockIdx.x * 64, n = blockIdx.y;

  const unsigned short* Khead = Kb + (size_t)n * LTOK * HDIM;
  const unsigned short* Vhead = Vb + (size_t)n * HDIM * LTOK;

  // ---- prologue ----
  {
    const int r = t >> 2, c = t & 3;
    const unsigned short* src = Qb + ((size_t)n * LTOK + l0 + r) * HDIM + c * 16;
    uint4 v0 = *(const uint4*)src;
    uint4 v1 = *(const uint4*)(src + 8);
    *(uint4*)&Q_s[r * 72 + c * 16] = v0;
    *(uint4*)&Q_s[r * 72 + c * 16 + 8] = v1;
  }
  __syncthreads();

  const int rowb = lane >> 3;
  const int srcc = (lane & 7) ^ rowb;
  const int vBb0 = w * 1024 + lane * 16;
  const int vr0 = vBb0 / 96, vc0 = (vBb0 % 96) >> 1;
  const int cw = 2 + w;  // Vt chunks 4,5 for w=2,3
  const int vBb1 = cw * 1024 + lane * 16;
  const int vr1 = vBb1 / 96, vc1 = (vBb1 % 96) >> 1;
  {
    // early tile-0 stage into K0/V0 (latency hides under bias compute)
    gld_lds16(K0 + w * 512, Khead + (size_t)(w * 8 + rowb) * HDIM + srcc * 8);
    if (w < 2)
      gld_lds16(K0 + (4 + w) * 512, Khead + (size_t)((4 + w) * 8 + rowb) * HDIM + srcc * 8);
    gld_lds16(V0 + w * 512, Vhead + (size_t)vr0 * LTOK + vc0);
    if (w >= 2)
      gld_lds16(V0 + cw * 512, Vhead + (size_t)vr1 * LTOK + vc1);
  }

  const s16x8 qf0 = *(const s16x8*)&Q_s[(w * 16 + p) * 72 + g * 8];
  const s16x8 qf1 = *(const s16x8*)&Q_s[(w * 16 + p) * 72 + 32 + g * 8];

  const int qh_lane = (l0 + lane) / 48;
#pragma unroll
  for (int i = 0; i < 12; ++i) {
    const int kt = w + 4 * i;
    const float* rrow = relh + (size_t)(qh_lane - kt + 47) * HDIM;
    float acc = 0.f;
#pragma unroll
    for (int c8 = 0; c8 < 8; ++c8) {
      s16x8 qv = *(const s16x8*)&Q_s[lane * 72 + c8 * 8];
      float4 ra = *(const float4*)&rrow[c8 * 8];
      float4 rb = *(const float4*)&rrow[c8 * 8 + 4];
      acc += b2f((unsigned short)qv[0]) * ra.x + b2f((unsigned short)qv[1]) * ra.y +
             b2f((unsigned short)qv[2]) * ra.z + b2f((unsigned short)qv[3]) * ra.w +
             b2f((unsigned short)qv[4]) * rb.x + b2f((unsigned short)qv[5]) * rb.y +
             b2f((unsigned short)qv[6]) * rb.z + b2f((unsigned short)qv[7]) * rb.w;
    }
    bh_t[kt * 64 + lane] = acc;
  }

  float bwreg[12];
  {
    const int qrow = w * 16 + p;
    const int qw_lane = (l0 + qrow) % 48;
#pragma unroll
    for (int mb = 0; mb < 3; ++mb)
#pragma unroll
      for (int jj = 0; jj < 4; ++jj) {
        const int j = 16 * mb + 4 * g + jj;
        const float* rrow = relw + (size_t)(qw_lane - j + 47) * HDIM;
        float acc = 0.f;
#pragma unroll
        for (int c8 = 0; c8 < 8; ++c8) {
          s16x8 qv = *(const s16x8*)&Q_s[qrow * 72 + c8 * 8];
          float4 ra = *(const float4*)&rrow[c8 * 8];
          float4 rb = *(const float4*)&rrow[c8 * 8 + 4];
          acc += b2f((unsigned short)qv[0]) * ra.x + b2f((unsigned short)qv[1]) * ra.y +
                 b2f((unsigned short)qv[2]) * ra.z + b2f((unsigned short)qv[3]) * ra.w +
                 b2f((unsigned short)qv[4]) * rb.x + b2f((unsigned short)qv[5]) * rb.y +
                 b2f((unsigned short)qv[6]) * rb.z + b2f((unsigned short)qv[7]) * rb.w;
        }
        bwreg[mb * 4 + jj] = acc;
      }
  }

  // one-time zero pads: P key range [48,64); Vt tails
  {
    uint2 z = {0u, 0u};
    *(uint2*)&P_lds[w * 16 * 72 + p * 72 + 48 + 4 * g] = z;
    if (t < 16) V0[64 * 48 + t] = 0;
    else if (t < 32) V1[64 * 48 + (t - 16)] = 0;
  }
  __syncthreads();  // drains tile-0 loads; Q_s dead after this point

  float m = -3e38f, lsum = 0.f;
  f32x4 accO[4] = {};
  const int sw0 = g ^ (p & 7);
  const int sw1 = (g + 4) ^ (p & 7);
  unsigned short* const Pw = P_lds + w * 16 * 72;

  unsigned short* Kc = K0; unsigned short* Vc = V0;
  unsigned short* Kn = K1; unsigned short* Vn = V1;

  for (int kt = 0; kt < 48; ++kt) {
    // stage tile kt+1 into Kn/Vn
    if (kt + 1 < 48) {
      const int ktn = kt + 1;
      gld_lds16(Kn + w * 512, Khead + (size_t)(ktn * 48 + w * 8 + rowb) * HDIM + srcc * 8);
      if (w < 2)
        gld_lds16(Kn + (4 + w) * 512,
                  Khead + (size_t)(ktn * 48 + (4 + w) * 8 + rowb) * HDIM + srcc * 8);
      gld_lds16(Vn + w * 512, Vhead + (size_t)vr0 * LTOK + ktn * 48 + vc0);
      if (w >= 2)
        gld_lds16(Vn + cw * 512, Vhead + (size_t)vr1 * LTOK + ktn * 48 + vc1);
    }

    // S^T = K . Q^T : D[key][q], col=p=q, row=4g+jj=key-in-16
    f32x4 st[3] = {};
    __builtin_amdgcn_s_setprio(1);
#pragma unroll
    for (int mb = 0; mb < 3; ++mb) {
      const int krow = (16 * mb + p) * 64;
      s16x8 kf0 = *(const s16x8*)&Kc[krow + sw0 * 8];
      s16x8 kf1 = *(const s16x8*)&Kc[krow + sw1 * 8];
      st[mb] = __builtin_amdgcn_mfma_f32_16x16x32_bf16(kf0, qf0, st[mb], 0, 0, 0);
      st[mb] = __builtin_amdgcn_mfma_f32_16x16x32_bf16(kf1, qf1, st[mb], 0, 0, 0);
    }
    __builtin_amdgcn_s_setprio(0);

    // bias + online softmax (per lane: q-row = w*16+p, 12 keys)
    const float bhv = bh_t[kt * 64 + w * 16 + p];
    float sv[12];
#pragma unroll
    for (int mb = 0; mb < 3; ++mb)
#pragma unroll
      for (int jj = 0; jj < 4; ++jj)
        sv[mb * 4 + jj] = st[mb][jj] * ATT_SCALE + bhv + bwreg[mb * 4 + jj];
    float tm = sv[0];
#pragma unroll
    for (int i = 1; i < 12; ++i) tm = fmaxf(tm, sv[i]);
    tm = fmaxf(tm, __shfl_xor(tm, 16, 64));
    tm = fmaxf(tm, __shfl_xor(tm, 32, 64));
    const float mn = fmaxf(m, tm);
    const float alpha = __expf(m - mn);
    m = mn;
    float pv[12], ps = 0.f;
#pragma unroll
    for (int i = 0; i < 12; ++i) { pv[i] = __expf(sv[i] - mn); ps += pv[i]; }
    ps += __shfl_xor(ps, 16, 64);
    ps += __shfl_xor(ps, 32, 64);
    lsum = lsum * alpha + ps;
#pragma unroll
    for (int db = 0; db < 4; ++db) accO[db] *= alpha;

    // P -> bf16 -> Pw rows (q=p), keys 16mb+4g+jj (pad zone pre-zeroed)
#pragma unroll
    for (int mb = 0; mb < 3; ++mb) {
      unsigned int lo = (unsigned int)f2b(pv[mb * 4 + 0]) | ((unsigned int)f2b(pv[mb * 4 + 1]) << 16);
      unsigned int hi = (unsigned int)f2b(pv[mb * 4 + 2]) | ((unsigned int)f2b(pv[mb * 4 + 3]) << 16);
      uint2 val = {lo, hi};
      *(uint2*)&Pw[p * 72 + 16 * mb + 4 * g] = val;
    }

    // PV: O^T[d][q] += Vt . P^T
    const s16x8 pf0 = *(const s16x8*)&Pw[p * 72 + g * 8];
    const s16x8 pf1 = *(const s16x8*)&Pw[p * 72 + 32 + g * 8];
    __builtin_amdgcn_s_setprio(1);
#pragma unroll
    for (int db = 0; db < 4; ++db) {
      const int vrow = (16 * db + p) * 48;
      s16x8 vf0 = *(const s16x8*)&Vc[vrow + g * 8];
      s16x8 vf1 = *(const s16x8*)&Vc[vrow + 32 + g * 8];
      accO[db] = __builtin_amdgcn_mfma_f32_16x16x32_bf16(vf0, pf0, accO[db], 0, 0, 0);
      accO[db] = __builtin_amdgcn_mfma_f32_16x16x32_bf16(vf1, pf1, accO[db], 0, 0, 0);
    }
    __builtin_amdgcn_s_setprio(0);
    __syncthreads();  // drains this step's stage loads; all waves done with Kc/Vc

    unsigned short* tk = Kc; Kc = Kn; Kn = tk;
    unsigned short* tv = Vc; Vc = Vn; Vn = tv;
  }

  // epilogue: lane's q-row = w*16+p; accO[db][jj] = O[q][16db+4g+jj]
  const float inv = 1.0f / lsum;
  unsigned short* orow = out + (size_t)(l0 + w * 16 + p) * CDIM + n * HDIM;
#pragma unroll
  for (int db = 0; db < 4; ++db) {
    unsigned int lo = (unsigned int)f2b(accO[db][0] * inv) | ((unsigned int)f2b(accO[db][1] * inv) << 16);
    unsigned int hi = (unsigned int)f2b(accO[db][2] * inv) | ((unsigned int)f2b(accO[db][3] * inv) << 16);
    uint2 val = {lo, hi};
    *(uint2*)&orow[16 * db + 4 * g] = val;
  }
}

// ---------------- launch ----------------
extern "C" void kernel_launch(void* const* d_in, const int* in_sizes, int n_in,
                              void* d_out, int out_size, void* d_ws, size_t ws_size,
                              hipStream_t stream) {
  const float* x     = (const float*)d_in[0];
  const float* ln1w  = (const float*)d_in[1];
  const float* ln1b  = (const float*)d_in[2];
  const float* qkvw  = (const float*)d_in[3];
  const float* qkvb  = (const float*)d_in[4];
  const float* relh  = (const float*)d_in[5];
  const float* relw  = (const float*)d_in[6];
  const float* projw = (const float*)d_in[7];
  const float* projb = (const float*)d_in[8];
  const float* ln2w  = (const float*)d_in[9];
  const float* ln2b  = (const float*)d_in[10];
  const float* fc1w  = (const float*)d_in[11];
  const float* fc1b  = (const float*)d_in[12];
  const float* fc2w  = (const float*)d_in[13];
  const float* fc2b  = (const float*)d_in[14];
  float* out = (float*)d_out;
  float* ws = (float*)d_ws;

  float* qkv = ws;                             // L*3C f32
  float* x1  = qkv + (size_t)LTOK * 3 * CDIM;  // L*C f32 (overlaid by Qb/Kb before proj)
  float* cs  = x1 + (size_t)LTOK * CDIM;
  float* sn  = cs + (size_t)LTOK * 32;
  unsigned short* h_bf    = (unsigned short*)(sn + (size_t)LTOK * 32);
  unsigned short* attn_bf = h_bf + (size_t)LTOK * CDIM;
  unsigned short* wq      = attn_bf + (size_t)LTOK * CDIM;
  unsigned short* wproj   = wq + (size_t)3 * CDIM * CDIM;
  unsigned short* wfc1    = wproj + (size_t)CDIM * CDIM;
  unsigned short* wfc2    = wfc1 + (size_t)4 * CDIM * CDIM;
  unsigned short* Qb      = (unsigned short*)x1;   // Qb+Kb fit x1 exactly
  unsigned short* Kb      = Qb + (size_t)NHEAD * LTOK * HDIM;
  unsigned short* Vb      = wq;                    // overlay: wq dead after qkv GEMM
  unsigned short* m1_bf   = (unsigned short*)qkv;  // overlay: qkv dead after prep

  f2b_kernel<<<(3 * CDIM * CDIM / 8 + 255) / 256, 256, 0, stream>>>(qkvw, wq, 3 * CDIM * CDIM);
  f2b_kernel<<<(CDIM * CDIM / 8 + 255) / 256, 256, 0, stream>>>(projw, wproj, CDIM * CDIM);
  f2b_kernel<<<(4 * CDIM * CDIM / 8 + 255) / 256, 256, 0, stream>>>(fc1w, wfc1, 4 * CDIM * CDIM);
  f2b_kernel<<<(4 * CDIM * CDIM / 8 + 255) / 256, 256, 0, stream>>>(fc2w, wfc2, 4 * CDIM * CDIM);

  ln_kernel<<<LTOK, 256, 0, stream>>>(x, ln1w, ln1b, h_bf);
  mfma_gemm<false, false, false><<<dim3(18, 18), 256, 0, stream>>>(
      h_bf, wq, qkvb, nullptr, qkv, LTOK, 3 * CDIM, CDIM);
  rope_cs_kernel<<<288, 256, 0, stream>>>(cs, sn);
  prep_kernel<<<dim3(36, 12), 256, 0, stream>>>(qkv, cs, sn, Qb, Kb, Vb);
  attn_mfma<<<dim3(36, 12), 256, 0, stream>>>(Qb, Kb, Vb, relh, relw, attn_bf);
  mfma_gemm<false, true, false><<<dim3(6, 18), 256, 0, stream>>>(
      attn_bf, wproj, projb, x, x1, LTOK, CDIM, CDIM);
  ln_kernel<<<LTOK, 256, 0, stream>>>(x1, ln2w, ln2b, h_bf);
  mfma_gemm<true, false, true><<<dim3(24, 18), 256, 0, stream>>>(
      h_bf, wfc1, fc1b, nullptr, m1_bf, LTOK, 4 * CDIM, CDIM);
  mfma_gemm<false, true, false><<<dim3(6, 18), 256, 0, stream>>>(
      m1_bf, wfc2, fc2b, x1, out, LTOK, CDIM, 4 * CDIM);
}

// Round 9
// 393.447 us; speedup vs baseline: 1.1069x; 1.0389x over previous
//
#include <hip/hip_runtime.h>
#include <math.h>

#define LTOK 2304
#define CDIM 768
#define NHEAD 12
#define HDIM 64
#define HS 48

static constexpr float ATT_SCALE = 0.125f;  // 64^-0.5

typedef short s16x8 __attribute__((ext_vector_type(8)));   // 8 bf16 bits (4 VGPRs)
typedef float f32x4 __attribute__((ext_vector_type(4)));

__device__ __forceinline__ unsigned short f2b(float f) {
  __bf16 b = (__bf16)f;   // RNE
  return __builtin_bit_cast(unsigned short, b);
}
__device__ __forceinline__ float b2f(unsigned short u) {
  unsigned int x = ((unsigned int)u) << 16;
  return __builtin_bit_cast(float, x);
}

__device__ __forceinline__ void gld_lds16(void* lds, const void* g) {
  __builtin_amdgcn_global_load_lds(
      (const __attribute__((address_space(1))) unsigned int*)g,
      (__attribute__((address_space(3))) unsigned int*)lds, 16, 0, 0);
}

// ---------------- fp32 -> bf16 convert (n % 8 == 0) ----------------
__global__ __launch_bounds__(256) void f2b_kernel(const float* __restrict__ in,
                                                  unsigned short* __restrict__ out, int n) {
  const int i = (blockIdx.x * 256 + threadIdx.x) * 8;
  if (i + 8 > n) return;
  float4 v0 = *(const float4*)(in + i);
  float4 v1 = *(const float4*)(in + i + 4);
  alignas(16) unsigned short o[8] = {f2b(v0.x), f2b(v0.y), f2b(v0.z), f2b(v0.w),
                                     f2b(v1.x), f2b(v1.y), f2b(v1.z), f2b(v1.w)};
  *(uint4*)(out + i) = *(const uint4*)o;
}

// ---------------- LayerNorm: fp32 in, bf16 out ----------------
__global__ __launch_bounds__(256) void ln_kernel(const float* __restrict__ x,
                                                 const float* __restrict__ w,
                                                 const float* __restrict__ b,
                                                 unsigned short* __restrict__ out) {
  const int row = blockIdx.x;
  const int t = threadIdx.x;
  const float* xr = x + (size_t)row * CDIM;
  float v0 = xr[t], v1 = xr[t + 256], v2 = xr[t + 512];
  float s = v0 + v1 + v2;
  float ss = v0 * v0 + v1 * v1 + v2 * v2;
#pragma unroll
  for (int off = 32; off > 0; off >>= 1) {
    s += __shfl_down(s, off, 64);
    ss += __shfl_down(ss, off, 64);
  }
  __shared__ float rs[4], rss[4];
  if ((t & 63) == 0) { rs[t >> 6] = s; rss[t >> 6] = ss; }
  __syncthreads();
  float S = rs[0] + rs[1] + rs[2] + rs[3];
  float SS = rss[0] + rss[1] + rss[2] + rss[3];
  const float inv_c = 1.0f / (float)CDIM;
  float mu = S * inv_c;
  float var = SS * inv_c - mu * mu;
  float inv = rsqrtf(var + 1e-5f);
  unsigned short* orow = out + (size_t)row * CDIM;
  orow[t]       = f2b((v0 - mu) * inv * w[t]       + b[t]);
  orow[t + 256] = f2b((v1 - mu) * inv * w[t + 256] + b[t + 256]);
  orow[t + 512] = f2b((v2 - mu) * inv * w[t + 512] + b[t + 512]);
}

// ---------------- bf16 MFMA GEMM (m97 structure) ----------------
template <bool GELU, bool RES, bool OUTBF>
__global__ __launch_bounds__(256) void mfma_gemm(const unsigned short* __restrict__ A,
                                                 const unsigned short* __restrict__ B,
                                                 const float* __restrict__ bias,
                                                 const float* __restrict__ res,
                                                 void* __restrict__ Cout,
                                                 int M, int N, int K) {
  __shared__ unsigned short As[128 * 32];
  __shared__ unsigned short Bs[128 * 32];
  const int t = threadIdx.x;
  const int lane = t & 63;
  const int w = t >> 6;
  const int wm = w >> 1, wn = w & 1;
  const int bm = blockIdx.y * 128, bn = blockIdx.x * 128;

  f32x4 acc[4][4] = {};

  const int c0 = 2 * w, c1 = 2 * w + 1;
  const int srow = lane >> 2;
  const int skof = (lane & 3) * 8;
  const unsigned short* Abase = A + (size_t)bm * K + skof;
  const unsigned short* Bbase = B + (size_t)bn * K + skof;
  const int lr = lane & 15, lk = (lane >> 4) * 8, lg = lane >> 4;

  for (int k0 = 0; k0 < K; k0 += 32) {
    gld_lds16(As + c0 * 512, Abase + (size_t)(c0 * 16 + srow) * K + k0);
    gld_lds16(As + c1 * 512, Abase + (size_t)(c1 * 16 + srow) * K + k0);
    gld_lds16(Bs + c0 * 512, Bbase + (size_t)(c0 * 16 + srow) * K + k0);
    gld_lds16(Bs + c1 * 512, Bbase + (size_t)(c1 * 16 + srow) * K + k0);
    __syncthreads();
    s16x8 a[4], b[4];
#pragma unroll
    for (int m = 0; m < 4; ++m)
      a[m] = *(const s16x8*)&As[(wm * 64 + m * 16 + lr) * 32 + lk];
#pragma unroll
    for (int n = 0; n < 4; ++n)
      b[n] = *(const s16x8*)&Bs[(wn * 64 + n * 16 + lr) * 32 + lk];
#pragma unroll
    for (int m = 0; m < 4; ++m)
#pragma unroll
      for (int n = 0; n < 4; ++n)
        acc[m][n] = __builtin_amdgcn_mfma_f32_16x16x32_bf16(a[m], b[n], acc[m][n], 0, 0, 0);
    __syncthreads();
  }

#pragma unroll
  for (int n = 0; n < 4; ++n) {
    const int col = bn + wn * 64 + n * 16 + lr;
    const float bc = bias[col];
#pragma unroll
    for (int m = 0; m < 4; ++m) {
#pragma unroll
      for (int j = 0; j < 4; ++j) {
        const int row = bm + wm * 64 + m * 16 + lg * 4 + j;
        float v = acc[m][n][j] + bc;
        if (GELU) v = 0.5f * v * (1.0f + erff(v * 0.70710678118654752f));
        if (RES) v += res[(size_t)row * N + col];
        if (OUTBF) ((unsigned short*)Cout)[(size_t)row * N + col] = f2b(v);
        else       ((float*)Cout)[(size_t)row * N + col] = v;
      }
    }
  }
}

// ---------------- RoPE cos/sin tables: [L][32] ----------------
__global__ __launch_bounds__(256) void rope_cs_kernel(float* __restrict__ cs,
                                                      float* __restrict__ sn) {
  const int idx = blockIdx.x * 256 + threadIdx.x;  // < 2304*32
  const int l = idx >> 5;
  const int i = idx & 31;
  const int j = i & 15;
  const float f = __expf(-(float)j * 0.57564627324851142f);
  const float coord = (i < 16) ? (float)(l % HS) : (float)(l / HS);
  const float ang = coord * f;
  cs[idx] = cosf(ang);
  sn[idx] = sinf(ang);
}

// ---------------- prep: fp32 qkv -> Qb,Kb [NH][L][64] (RoPE) + Vb [NH][64][L] -------
// grid (36, 12), 256 threads
__global__ __launch_bounds__(256) void prep_kernel(const float* __restrict__ qkv,
                                                   const float* __restrict__ cs,
                                                   const float* __restrict__ sn,
                                                   unsigned short* __restrict__ Qb,
                                                   unsigned short* __restrict__ Kb,
                                                   unsigned short* __restrict__ Vb) {
  __shared__ unsigned short Vs[64 * 72];
  const int t = threadIdx.x;
  const int l0 = blockIdx.x * 64, n = blockIdx.y;
  const int r = t >> 2, c = t & 3;
  const int l = l0 + r;
  const float* base = qkv + (size_t)l * (3 * CDIM) + n * HDIM + c * 16;
#pragma unroll
  for (int pq = 0; pq < 2; ++pq) {
    const float* src = base + pq * CDIM;
    alignas(16) unsigned short o[16];
#pragma unroll
    for (int i = 0; i < 4; ++i) {
      float4 v = *(const float4*)(src + i * 4);
      const int pr = c * 8 + i * 2;
      const float c0 = cs[l * 32 + pr],     s0 = sn[l * 32 + pr];
      const float c1 = cs[l * 32 + pr + 1], s1 = sn[l * 32 + pr + 1];
      o[i * 4 + 0] = f2b(v.x * c0 - v.y * s0);
      o[i * 4 + 1] = f2b(v.x * s0 + v.y * c0);
      o[i * 4 + 2] = f2b(v.z * c1 - v.w * s1);
      o[i * 4 + 3] = f2b(v.z * s1 + v.w * c1);
    }
    unsigned short* dst = (pq ? Kb : Qb) + ((size_t)n * LTOK + l) * HDIM + c * 16;
    *(uint4*)dst = *(const uint4*)o;
    *(uint4*)(dst + 8) = *(const uint4*)(o + 8);
  }
  // V transpose via LDS (coalesced in and out)
  {
    const float* vsrc = base + 2 * CDIM;
    alignas(16) unsigned short vo[16];
#pragma unroll
    for (int i = 0; i < 4; ++i) {
      float4 v = *(const float4*)(vsrc + i * 4);
      vo[i * 4 + 0] = f2b(v.x); vo[i * 4 + 1] = f2b(v.y);
      vo[i * 4 + 2] = f2b(v.z); vo[i * 4 + 3] = f2b(v.w);
    }
    *(uint4*)&Vs[r * 72 + c * 16] = *(const uint4*)vo;
    *(uint4*)&Vs[r * 72 + c * 16 + 8] = *(const uint4*)(vo + 8);
  }
  __syncthreads();
  {
    const int d = t >> 2, kc = (t & 3) * 16;
    alignas(16) unsigned short o[16];
#pragma unroll
    for (int i = 0; i < 16; ++i) o[i] = Vs[(kc + i) * 72 + d];
    unsigned short* dst = Vb + ((size_t)n * HDIM + d) * LTOK + l0 + kc;
    *(uint4*)dst = *(const uint4*)o;
    *(uint4*)(dst + 8) = *(const uint4*)(o + 8);
  }
}

// ---------------- MFMA flash attention: single LDS buffer + REGISTER prefetch ------
// grid (36, 12), 256 threads = 4 waves x 16 q-rows.
// Per iter: { issue tile kt+1 global loads -> named regs ; compute tile kt ;
//             barrier (vmcnt drain overlaps compute) ; ds_write regs ; barrier }.
// Static __shared__ arrays, one body copy, no loop-carried pointers (R6/R7/R8's
// dbuf formulations all spilled to scratch: 140-290MB WRITE_SIZE).
// K layout: [48][64] shorts, ds_write dest-swizzled chunk = c ^ (row&7).
// V layout: [64] rows x stride 56 shorts (112B: kills 4-way bank conflict of 96B),
//           keys [48,56) pad + tail zeroed once (NaN-safe: P keys 48-63 are zero).
// Q_s (64x72) overlays P_lds (4x16x72) -- Q dead before P first written.
__global__ __launch_bounds__(256) void attn_mfma(const unsigned short* __restrict__ Qb,
                                                 const unsigned short* __restrict__ Kb,
                                                 const unsigned short* __restrict__ Vb,
                                                 const float* __restrict__ relh,
                                                 const float* __restrict__ relw,
                                                 unsigned short* __restrict__ out) {
  __shared__ unsigned short K_lds[48 * 64];
  __shared__ unsigned short V_lds[64 * 56 + 16];
  __shared__ unsigned short P_lds[4][16 * 72];
  __shared__ float bh_t[48 * 64];

  const int t = threadIdx.x;
  const int lane = t & 63, w = t >> 6;
  const int p = lane & 15, g = lane >> 4;
  const int l0 = blockIdx.x * 64, n = blockIdx.y;

  const unsigned short* Khead = Kb + (size_t)n * LTOK * HDIM;
  const unsigned short* Vhead = Vb + (size_t)n * HDIM * LTOK;
  unsigned short* const Q_s = &P_lds[0][0];

  // ---- stage Q into padded Q_s (overlays P) ----
  {
    const int r = t >> 2, c = t & 3;
    const unsigned short* src = Qb + ((size_t)n * LTOK + l0 + r) * HDIM + c * 16;
    uint4 v0 = *(const uint4*)src;
    uint4 v1 = *(const uint4*)(src + 8);
    *(uint4*)&Q_s[r * 72 + c * 16] = v0;
    *(uint4*)&Q_s[r * 72 + c * 16 + 8] = v1;
  }
  __syncthreads();

  // ---- per-thread staging geometry (loop-invariant) ----
  // K: 384 16B-chunks; thread t owns chunk t, and (t<128) chunk 256+t.
  const int krow0 = t >> 3, kc0 = t & 7;
  const int kdst0 = krow0 * 64 + (kc0 ^ (krow0 & 7)) * 8;
  const unsigned short* kgp0 = Khead + krow0 * HDIM + kc0 * 8;
  const int krow1 = 32 + (t >> 3);
  const int kdst1 = krow1 * 64 + ((t & 7) ^ (krow1 & 7)) * 8;
  const unsigned short* kgp1 = Khead + krow1 * HDIM + (t & 7) * 8;
  // V: 384 16B-chunks of the 64x48 tile (96B rows); LDS stride 56 shorts.
  const int vr0 = t / 6, vq0 = (t % 6) * 8;
  const int vdst0 = vr0 * 56 + vq0;
  const unsigned short* vgp0 = Vhead + (size_t)vr0 * LTOK + vq0;
  const int jv1 = 256 + t;
  const int vr1 = jv1 / 6, vq1 = (jv1 % 6) * 8;
  const int vdst1 = vr1 * 56 + vq1;
  const unsigned short* vgp1 = Vhead + (size_t)vr1 * LTOK + vq1;

  // ---- issue tile-0 loads (latency hides under bias compute) ----
  uint4 kA = *(const uint4*)kgp0;
  uint4 vA = *(const uint4*)vgp0;
  uint4 kB = {0, 0, 0, 0}, vB = {0, 0, 0, 0};
  if (w < 2) {
    kB = *(const uint4*)kgp1;
    vB = *(const uint4*)vgp1;
  }

  const s16x8 qf0 = *(const s16x8*)&Q_s[(w * 16 + p) * 72 + g * 8];
  const s16x8 qf1 = *(const s16x8*)&Q_s[(w * 16 + p) * 72 + 32 + g * 8];

  const int qh_lane = (l0 + lane) / 48;
#pragma unroll
  for (int i = 0; i < 12; ++i) {
    const int kt = w + 4 * i;
    const float* rrow = relh + (size_t)(qh_lane - kt + 47) * HDIM;
    float acc = 0.f;
#pragma unroll
    for (int c8 = 0; c8 < 8; ++c8) {
      s16x8 qv = *(const s16x8*)&Q_s[lane * 72 + c8 * 8];
      float4 ra = *(const float4*)&rrow[c8 * 8];
      float4 rb = *(const float4*)&rrow[c8 * 8 + 4];
      acc += b2f((unsigned short)qv[0]) * ra.x + b2f((unsigned short)qv[1]) * ra.y +
             b2f((unsigned short)qv[2]) * ra.z + b2f((unsigned short)qv[3]) * ra.w +
             b2f((unsigned short)qv[4]) * rb.x + b2f((unsigned short)qv[5]) * rb.y +
             b2f((unsigned short)qv[6]) * rb.z + b2f((unsigned short)qv[7]) * rb.w;
    }
    bh_t[kt * 64 + lane] = acc;
  }

  float bwreg[12];
  {
    const int qrow = w * 16 + p;
    const int qw_lane = (l0 + qrow) % 48;
#pragma unroll
    for (int mb = 0; mb < 3; ++mb)
#pragma unroll
      for (int jj = 0; jj < 4; ++jj) {
        const int j = 16 * mb + 4 * g + jj;
        const float* rrow = relw + (size_t)(qw_lane - j + 47) * HDIM;
        float acc = 0.f;
#pragma unroll
        for (int c8 = 0; c8 < 8; ++c8) {
          s16x8 qv = *(const s16x8*)&Q_s[qrow * 72 + c8 * 8];
          float4 ra = *(const float4*)&rrow[c8 * 8];
          float4 rb = *(const float4*)&rrow[c8 * 8 + 4];
          acc += b2f((unsigned short)qv[0]) * ra.x + b2f((unsigned short)qv[1]) * ra.y +
                 b2f((unsigned short)qv[2]) * ra.z + b2f((unsigned short)qv[3]) * ra.w +
                 b2f((unsigned short)qv[4]) * rb.x + b2f((unsigned short)qv[5]) * rb.y +
                 b2f((unsigned short)qv[6]) * rb.z + b2f((unsigned short)qv[7]) * rb.w;
        }
        bwreg[mb * 4 + jj] = acc;
      }
  }
  __syncthreads();  // Q_s dead; P region may now be initialized

  // ---- one-time zero pads + write tile 0 ----
  {
    const uint4 z4 = {0u, 0u, 0u, 0u};
    const uint2 z2 = {0u, 0u};
    *(uint2*)&P_lds[w][p * 72 + 48 + 4 * g] = z2;   // P keys [48,64) = 0
    if (t < 64) *(uint4*)&V_lds[t * 56 + 48] = z4;  // V row pads [48,56) = 0
    if (t == 64) *(uint4*)&V_lds[64 * 56] = z4;     // V tail
    *(uint4*)&K_lds[kdst0] = kA;
    *(uint4*)&V_lds[vdst0] = vA;
    if (w < 2) {
      *(uint4*)&K_lds[kdst1] = kB;
      *(uint4*)&V_lds[vdst1] = vB;
    }
  }
  __syncthreads();

  float m = -3e38f, lsum = 0.f;
  f32x4 accO[4] = {};
  const int sw0 = g ^ (p & 7);
  const int sw1 = (g + 4) ^ (p & 7);
  unsigned short* const Pw = &P_lds[w][0];

  for (int kt = 0; kt < 48; ++kt) {
    // issue tile kt+1 loads into named regs (drained at the post-compute barrier)
    uint4 nkA = {0, 0, 0, 0}, nvA = {0, 0, 0, 0}, nkB = {0, 0, 0, 0}, nvB = {0, 0, 0, 0};
    if (kt < 47) {
      const size_t ko = (size_t)(kt + 1) * 48 * HDIM;
      const size_t vo = (size_t)(kt + 1) * 48;
      nkA = *(const uint4*)(kgp0 + ko);
      nvA = *(const uint4*)(vgp0 + vo);
      if (w < 2) {
        nkB = *(const uint4*)(kgp1 + ko);
        nvB = *(const uint4*)(vgp1 + vo);
      }
    }

    // S^T = K . Q^T : D[key][q], col=p=q, row=4g+jj=key-in-16
    f32x4 st[3] = {};
    __builtin_amdgcn_s_setprio(1);
#pragma unroll
    for (int mb = 0; mb < 3; ++mb) {
      const int krow = (16 * mb + p) * 64;
      s16x8 kf0 = *(const s16x8*)&K_lds[krow + sw0 * 8];
      s16x8 kf1 = *(const s16x8*)&K_lds[krow + sw1 * 8];
      st[mb] = __builtin_amdgcn_mfma_f32_16x16x32_bf16(kf0, qf0, st[mb], 0, 0, 0);
      st[mb] = __builtin_amdgcn_mfma_f32_16x16x32_bf16(kf1, qf1, st[mb], 0, 0, 0);
    }
    __builtin_amdgcn_s_setprio(0);

    // bias + online softmax (per lane: q-row = w*16+p, 12 keys)
    const float bhv = bh_t[kt * 64 + w * 16 + p];
    float sv[12];
#pragma unroll
    for (int mb = 0; mb < 3; ++mb)
#pragma unroll
      for (int jj = 0; jj < 4; ++jj)
        sv[mb * 4 + jj] = st[mb][jj] * ATT_SCALE + bhv + bwreg[mb * 4 + jj];
    float tm = sv[0];
#pragma unroll
    for (int i = 1; i < 12; ++i) tm = fmaxf(tm, sv[i]);
    tm = fmaxf(tm, __shfl_xor(tm, 16, 64));
    tm = fmaxf(tm, __shfl_xor(tm, 32, 64));
    const float mn = fmaxf(m, tm);
    const float alpha = __expf(m - mn);
    m = mn;
    float pv[12], ps = 0.f;
#pragma unroll
    for (int i = 0; i < 12; ++i) { pv[i] = __expf(sv[i] - mn); ps += pv[i]; }
    ps += __shfl_xor(ps, 16, 64);
    ps += __shfl_xor(ps, 32, 64);
    lsum = lsum * alpha + ps;
#pragma unroll
    for (int db = 0; db < 4; ++db) accO[db] *= alpha;

    // P -> bf16 -> Pw rows (q=p), keys 16mb+4g+jj (pad zone pre-zeroed)
#pragma unroll
    for (int mb = 0; mb < 3; ++mb) {
      unsigned int lo = (unsigned int)f2b(pv[mb * 4 + 0]) | ((unsigned int)f2b(pv[mb * 4 + 1]) << 16);
      unsigned int hi = (unsigned int)f2b(pv[mb * 4 + 2]) | ((unsigned int)f2b(pv[mb * 4 + 3]) << 16);
      uint2 val = {lo, hi};
      *(uint2*)&Pw[p * 72 + 16 * mb + 4 * g] = val;
    }

    // PV: O^T[d][q] += Vt . P^T   (V stride 56)
    const s16x8 pf0 = *(const s16x8*)&Pw[p * 72 + g * 8];
    const s16x8 pf1 = *(const s16x8*)&Pw[p * 72 + 32 + g * 8];
    __builtin_amdgcn_s_setprio(1);
#pragma unroll
    for (int db = 0; db < 4; ++db) {
      const int vrow = (16 * db + p) * 56;
      s16x8 vf0 = *(const s16x8*)&V_lds[vrow + g * 8];
      s16x8 vf1 = *(const s16x8*)&V_lds[vrow + 32 + g * 8];
      accO[db] = __builtin_amdgcn_mfma_f32_16x16x32_bf16(vf0, pf0, accO[db], 0, 0, 0);
      accO[db] = __builtin_amdgcn_mfma_f32_16x16x32_bf16(vf1, pf1, accO[db], 0, 0, 0);
    }
    __builtin_amdgcn_s_setprio(0);

    __syncthreads();  // all waves done reading K/V LDS; drains prefetch loads too
    if (kt < 47) {
      *(uint4*)&K_lds[kdst0] = nkA;
      *(uint4*)&V_lds[vdst0] = nvA;
      if (w < 2) {
        *(uint4*)&K_lds[kdst1] = nkB;
        *(uint4*)&V_lds[vdst1] = nvB;
      }
    }
    __syncthreads();  // tile kt+1 visible
  }

  // epilogue: lane's q-row = w*16+p; accO[db][jj] = O[q][16db+4g+jj]
  const float inv = 1.0f / lsum;
  unsigned short* orow = out + (size_t)(l0 + w * 16 + p) * CDIM + n * HDIM;
#pragma unroll
  for (int db = 0; db < 4; ++db) {
    unsigned int lo = (unsigned int)f2b(accO[db][0] * inv) | ((unsigned int)f2b(accO[db][1] * inv) << 16);
    unsigned int hi = (unsigned int)f2b(accO[db][2] * inv) | ((unsigned int)f2b(accO[db][3] * inv) << 16);
    uint2 val = {lo, hi};
    *(uint2*)&orow[16 * db + 4 * g] = val;
  }
}

// ---------------- launch ----------------
extern "C" void kernel_launch(void* const* d_in, const int* in_sizes, int n_in,
                              void* d_out, int out_size, void* d_ws, size_t ws_size,
                              hipStream_t stream) {
  const float* x     = (const float*)d_in[0];
  const float* ln1w  = (const float*)d_in[1];
  const float* ln1b  = (const float*)d_in[2];
  const float* qkvw  = (const float*)d_in[3];
  const float* qkvb  = (const float*)d_in[4];
  const float* relh  = (const float*)d_in[5];
  const float* relw  = (const float*)d_in[6];
  const float* projw = (const float*)d_in[7];
  const float* projb = (const float*)d_in[8];
  const float* ln2w  = (const float*)d_in[9];
  const float* ln2b  = (const float*)d_in[10];
  const float* fc1w  = (const float*)d_in[11];
  const float* fc1b  = (const float*)d_in[12];
  const float* fc2w  = (const float*)d_in[13];
  const float* fc2b  = (const float*)d_in[14];
  float* out = (float*)d_out;
  float* ws = (float*)d_ws;

  float* qkv = ws;                             // L*3C f32
  float* x1  = qkv + (size_t)LTOK * 3 * CDIM;  // L*C f32 (overlaid by Qb/Kb before proj)
  float* cs  = x1 + (size_t)LTOK * CDIM;
  float* sn  = cs + (size_t)LTOK * 32;
  unsigned short* h_bf    = (unsigned short*)(sn + (size_t)LTOK * 32);
  unsigned short* attn_bf = h_bf + (size_t)LTOK * CDIM;
  unsigned short* wq      = attn_bf + (size_t)LTOK * CDIM;
  unsigned short* wproj   = wq + (size_t)3 * CDIM * CDIM;
  unsigned short* wfc1    = wproj + (size_t)CDIM * CDIM;
  unsigned short* wfc2    = wfc1 + (size_t)4 * CDIM * CDIM;
  unsigned short* Qb      = (unsigned short*)x1;   // Qb+Kb fit x1 exactly
  unsigned short* Kb      = Qb + (size_t)NHEAD * LTOK * HDIM;
  unsigned short* Vb      = wq;                    // overlay: wq dead after qkv GEMM
  unsigned short* m1_bf   = (unsigned short*)qkv;  // overlay: qkv dead after prep

  f2b_kernel<<<(3 * CDIM * CDIM / 8 + 255) / 256, 256, 0, stream>>>(qkvw, wq, 3 * CDIM * CDIM);
  f2b_kernel<<<(CDIM * CDIM / 8 + 255) / 256, 256, 0, stream>>>(projw, wproj, CDIM * CDIM);
  f2b_kernel<<<(4 * CDIM * CDIM / 8 + 255) / 256, 256, 0, stream>>>(fc1w, wfc1, 4 * CDIM * CDIM);
  f2b_kernel<<<(4 * CDIM * CDIM / 8 + 255) / 256, 256, 0, stream>>>(fc2w, wfc2, 4 * CDIM * CDIM);

  ln_kernel<<<LTOK, 256, 0, stream>>>(x, ln1w, ln1b, h_bf);
  mfma_gemm<false, false, false><<<dim3(18, 18), 256, 0, stream>>>(
      h_bf, wq, qkvb, nullptr, qkv, LTOK, 3 * CDIM, CDIM);
  rope_cs_kernel<<<288, 256, 0, stream>>>(cs, sn);
  prep_kernel<<<dim3(36, 12), 256, 0, stream>>>(qkv, cs, sn, Qb, Kb, Vb);
  attn_mfma<<<dim3(36, 12), 256, 0, stream>>>(Qb, Kb, Vb, relh, relw, attn_bf);
  mfma_gemm<false, true, false><<<dim3(6, 18), 256, 0, stream>>>(
      attn_bf, wproj, projb, x, x1, LTOK, CDIM, CDIM);
  ln_kernel<<<LTOK, 256, 0, stream>>>(x1, ln2w, ln2b, h_bf);
  mfma_gemm<true, false, true><<<dim3(24, 18), 256, 0, stream>>>(
      h_bf, wfc1, fc1b, nullptr, m1_bf, LTOK, 4 * CDIM, CDIM);
  mfma_gemm<false, true, false><<<dim3(6, 18), 256, 0, stream>>>(
      m1_bf, wfc2, fc2b, x1, out, LTOK, CDIM, 4 * CDIM);
}

// Round 10
// 291.850 us; speedup vs baseline: 1.4922x; 1.3481x over previous
//
#include <hip/hip_runtime.h>
#include <math.h>

#define LTOK 2304
#define CDIM 768
#define NHEAD 12
#define HDIM 64
#define HS 48

static constexpr float ATT_SCALE = 0.125f;  // 64^-0.5

typedef short s16x8 __attribute__((ext_vector_type(8)));   // 8 bf16 bits (4 VGPRs)
typedef float f32x4 __attribute__((ext_vector_type(4)));

__device__ __forceinline__ unsigned short f2b(float f) {
  __bf16 b = (__bf16)f;   // RNE
  return __builtin_bit_cast(unsigned short, b);
}
__device__ __forceinline__ float b2f(unsigned short u) {
  unsigned int x = ((unsigned int)u) << 16;
  return __builtin_bit_cast(float, x);
}

__device__ __forceinline__ void gld_lds16(void* lds, const void* g) {
  __builtin_amdgcn_global_load_lds(
      (const __attribute__((address_space(1))) unsigned int*)g,
      (__attribute__((address_space(3))) unsigned int*)lds, 16, 0, 0);
}

// ---------------- fp32 -> bf16 convert (n % 8 == 0) ----------------
__global__ __launch_bounds__(256) void f2b_kernel(const float* __restrict__ in,
                                                  unsigned short* __restrict__ out, int n) {
  const int i = (blockIdx.x * 256 + threadIdx.x) * 8;
  if (i + 8 > n) return;
  float4 v0 = *(const float4*)(in + i);
  float4 v1 = *(const float4*)(in + i + 4);
  alignas(16) unsigned short o[8] = {f2b(v0.x), f2b(v0.y), f2b(v0.z), f2b(v0.w),
                                     f2b(v1.x), f2b(v1.y), f2b(v1.z), f2b(v1.w)};
  *(uint4*)(out + i) = *(const uint4*)o;
}

// ---------------- LayerNorm: fp32 in, bf16 out ----------------
__global__ __launch_bounds__(256) void ln_kernel(const float* __restrict__ x,
                                                 const float* __restrict__ w,
                                                 const float* __restrict__ b,
                                                 unsigned short* __restrict__ out) {
  const int row = blockIdx.x;
  const int t = threadIdx.x;
  const float* xr = x + (size_t)row * CDIM;
  float v0 = xr[t], v1 = xr[t + 256], v2 = xr[t + 512];
  float s = v0 + v1 + v2;
  float ss = v0 * v0 + v1 * v1 + v2 * v2;
#pragma unroll
  for (int off = 32; off > 0; off >>= 1) {
    s += __shfl_down(s, off, 64);
    ss += __shfl_down(ss, off, 64);
  }
  __shared__ float rs[4], rss[4];
  if ((t & 63) == 0) { rs[t >> 6] = s; rss[t >> 6] = ss; }
  __syncthreads();
  float S = rs[0] + rs[1] + rs[2] + rs[3];
  float SS = rss[0] + rss[1] + rss[2] + rss[3];
  const float inv_c = 1.0f / (float)CDIM;
  float mu = S * inv_c;
  float var = SS * inv_c - mu * mu;
  float inv = rsqrtf(var + 1e-5f);
  unsigned short* orow = out + (size_t)row * CDIM;
  orow[t]       = f2b((v0 - mu) * inv * w[t]       + b[t]);
  orow[t + 256] = f2b((v1 - mu) * inv * w[t + 256] + b[t + 256]);
  orow[t + 512] = f2b((v2 - mu) * inv * w[t + 512] + b[t + 512]);
}

// ---------------- bf16 MFMA GEMM (m97 structure) ----------------
template <bool GELU, bool RES, bool OUTBF>
__global__ __launch_bounds__(256) void mfma_gemm(const unsigned short* __restrict__ A,
                                                 const unsigned short* __restrict__ B,
                                                 const float* __restrict__ bias,
                                                 const float* __restrict__ res,
                                                 void* __restrict__ Cout,
                                                 int M, int N, int K) {
  __shared__ unsigned short As[128 * 32];
  __shared__ unsigned short Bs[128 * 32];
  const int t = threadIdx.x;
  const int lane = t & 63;
  const int w = t >> 6;
  const int wm = w >> 1, wn = w & 1;
  const int bm = blockIdx.y * 128, bn = blockIdx.x * 128;

  f32x4 acc[4][4] = {};

  const int c0 = 2 * w, c1 = 2 * w + 1;
  const int srow = lane >> 2;
  const int skof = (lane & 3) * 8;
  const unsigned short* Abase = A + (size_t)bm * K + skof;
  const unsigned short* Bbase = B + (size_t)bn * K + skof;
  const int lr = lane & 15, lk = (lane >> 4) * 8, lg = lane >> 4;

  for (int k0 = 0; k0 < K; k0 += 32) {
    gld_lds16(As + c0 * 512, Abase + (size_t)(c0 * 16 + srow) * K + k0);
    gld_lds16(As + c1 * 512, Abase + (size_t)(c1 * 16 + srow) * K + k0);
    gld_lds16(Bs + c0 * 512, Bbase + (size_t)(c0 * 16 + srow) * K + k0);
    gld_lds16(Bs + c1 * 512, Bbase + (size_t)(c1 * 16 + srow) * K + k0);
    __syncthreads();
    s16x8 a[4], b[4];
#pragma unroll
    for (int m = 0; m < 4; ++m)
      a[m] = *(const s16x8*)&As[(wm * 64 + m * 16 + lr) * 32 + lk];
#pragma unroll
    for (int n = 0; n < 4; ++n)
      b[n] = *(const s16x8*)&Bs[(wn * 64 + n * 16 + lr) * 32 + lk];
#pragma unroll
    for (int m = 0; m < 4; ++m)
#pragma unroll
      for (int n = 0; n < 4; ++n)
        acc[m][n] = __builtin_amdgcn_mfma_f32_16x16x32_bf16(a[m], b[n], acc[m][n], 0, 0, 0);
    __syncthreads();
  }

#pragma unroll
  for (int n = 0; n < 4; ++n) {
    const int col = bn + wn * 64 + n * 16 + lr;
    const float bc = bias[col];
#pragma unroll
    for (int m = 0; m < 4; ++m) {
#pragma unroll
      for (int j = 0; j < 4; ++j) {
        const int row = bm + wm * 64 + m * 16 + lg * 4 + j;
        float v = acc[m][n][j] + bc;
        if (GELU) v = 0.5f * v * (1.0f + erff(v * 0.70710678118654752f));
        if (RES) v += res[(size_t)row * N + col];
        if (OUTBF) ((unsigned short*)Cout)[(size_t)row * N + col] = f2b(v);
        else       ((float*)Cout)[(size_t)row * N + col] = v;
      }
    }
  }
}

// ---------------- RoPE cos/sin tables: [L][32] ----------------
__global__ __launch_bounds__(256) void rope_cs_kernel(float* __restrict__ cs,
                                                      float* __restrict__ sn) {
  const int idx = blockIdx.x * 256 + threadIdx.x;  // < 2304*32
  const int l = idx >> 5;
  const int i = idx & 31;
  const int j = i & 15;
  const float f = __expf(-(float)j * 0.57564627324851142f);
  const float coord = (i < 16) ? (float)(l % HS) : (float)(l / HS);
  const float ang = coord * f;
  cs[idx] = cosf(ang);
  sn[idx] = sinf(ang);
}

// ---------------- prep: qkv -> Qb,Kb [NH][L][64] (RoPE) + Vb subtiled --------------
// Vb layout: [NH][L/8 keychunks][64 d][8 keys]  (16B units = one (kc,d) cell)
// grid (36, 12), 256 threads
__global__ __launch_bounds__(256) void prep_kernel(const float* __restrict__ qkv,
                                                   const float* __restrict__ cs,
                                                   const float* __restrict__ sn,
                                                   unsigned short* __restrict__ Qb,
                                                   unsigned short* __restrict__ Kb,
                                                   unsigned short* __restrict__ Vb) {
  __shared__ unsigned short Vs[64 * 72];
  const int t = threadIdx.x;
  const int l0 = blockIdx.x * 64, n = blockIdx.y;
  const int r = t >> 2, c = t & 3;
  const int l = l0 + r;
  const float* base = qkv + (size_t)l * (3 * CDIM) + n * HDIM + c * 16;
#pragma unroll
  for (int pq = 0; pq < 2; ++pq) {
    const float* src = base + pq * CDIM;
    alignas(16) unsigned short o[16];
#pragma unroll
    for (int i = 0; i < 4; ++i) {
      float4 v = *(const float4*)(src + i * 4);
      const int pr = c * 8 + i * 2;
      const float c0 = cs[l * 32 + pr],     s0 = sn[l * 32 + pr];
      const float c1 = cs[l * 32 + pr + 1], s1 = sn[l * 32 + pr + 1];
      o[i * 4 + 0] = f2b(v.x * c0 - v.y * s0);
      o[i * 4 + 1] = f2b(v.x * s0 + v.y * c0);
      o[i * 4 + 2] = f2b(v.z * c1 - v.w * s1);
      o[i * 4 + 3] = f2b(v.z * s1 + v.w * c1);
    }
    unsigned short* dst = (pq ? Kb : Qb) + ((size_t)n * LTOK + l) * HDIM + c * 16;
    *(uint4*)dst = *(const uint4*)o;
    *(uint4*)(dst + 8) = *(const uint4*)(o + 8);
  }
  // V transpose via LDS, then write subtiled [kc][d][8]
  {
    const float* vsrc = base + 2 * CDIM;
    alignas(16) unsigned short vo[16];
#pragma unroll
    for (int i = 0; i < 4; ++i) {
      float4 v = *(const float4*)(vsrc + i * 4);
      vo[i * 4 + 0] = f2b(v.x); vo[i * 4 + 1] = f2b(v.y);
      vo[i * 4 + 2] = f2b(v.z); vo[i * 4 + 3] = f2b(v.w);
    }
    *(uint4*)&Vs[r * 72 + c * 16] = *(const uint4*)vo;
    *(uint4*)&Vs[r * 72 + c * 16 + 8] = *(const uint4*)(vo + 8);
  }
  __syncthreads();
  {
    const int d = t >> 2, kc16 = (t & 3) * 16;
    alignas(16) unsigned short o[16];
#pragma unroll
    for (int i = 0; i < 16; ++i) o[i] = Vs[(kc16 + i) * 72 + d];
    const int kb = (l0 + kc16) >> 3;  // global key-chunk
    unsigned short* dst0 = Vb + ((size_t)(n * (LTOK / 8) + kb) * 64 + d) * 8;
    unsigned short* dst1 = Vb + ((size_t)(n * (LTOK / 8) + kb + 1) * 64 + d) * 8;
    *(uint4*)dst0 = *(const uint4*)o;
    *(uint4*)dst1 = *(const uint4*)(o + 8);
  }
}

// ---------------- MFMA flash attention, KVB=96 staged / two 48-key halves ----------
// grid (36, 12), 256 threads = 4 waves x 16 q-rows.  R4 schedule (stage -> barrier ->
// compute -> barrier) with half the stages: one gld_lds stage per 96 keys; the inner
// half-body is R4's exact (st[3]/sv[12]/pv[12]) to keep VGPR ~70 (R6-R9's pipelining
// variants all scratch-spilled).  #pragma unroll 1 pins both loops against unrolling.
// LDS map (bytes):
//   K   @     0 (12288)  96 rows x 64 shorts, chunk-XOR swizzle (src side)
//   V   @ 12288 (14336)  subtiled [14 kc][64 d][8 keys]; kc 12,13 = zero pads
//   P   @ 26624 ( 9216)  4 waves x [16 q][72]
//   bh  @ 35840 (12288)  [48 kh-tiles][64 q] f32
//   Q_s overlays P @ 26624 (9216; dead after prologue)        total 48128 -> 3 blk/CU
__global__ __launch_bounds__(256) void attn_mfma(const unsigned short* __restrict__ Qb,
                                                 const unsigned short* __restrict__ Kb,
                                                 const unsigned short* __restrict__ Vb,
                                                 const float* __restrict__ relh,
                                                 const float* __restrict__ relw,
                                                 unsigned short* __restrict__ out) {
  __shared__ __align__(16) unsigned char smem[48128];
  unsigned short* const K_lds = (unsigned short*)(smem);
  unsigned short* const V_lds = (unsigned short*)(smem + 12288);
  unsigned short* const P_lds = (unsigned short*)(smem + 26624);
  float* const bh_t = (float*)(smem + 35840);
  unsigned short* const Q_s = (unsigned short*)(smem + 26624);  // overlays P

  const int t = threadIdx.x;
  const int lane = t & 63, w = t >> 6;
  const int p = lane & 15, g = lane >> 4;
  const int l0 = blockIdx.x * 64, n = blockIdx.y;

  const unsigned short* Khead = Kb + (size_t)n * LTOK * HDIM;
  const unsigned short* Vhead = Vb + (size_t)n * (LTOK / 8) * 64 * 8;

  // ---- stage Q into padded Q_s (overlays P) ----
  {
    const int r = t >> 2, c = t & 3;
    const unsigned short* src = Qb + ((size_t)n * LTOK + l0 + r) * HDIM + c * 16;
    uint4 v0 = *(const uint4*)src;
    uint4 v1 = *(const uint4*)(src + 8);
    *(uint4*)&Q_s[r * 72 + c * 16] = v0;
    *(uint4*)&Q_s[r * 72 + c * 16 + 8] = v1;
  }
  __syncthreads();

  // ---- staging geometry ----
  const int rowb = lane >> 3;
  const int srcc = (lane & 7) ^ rowb;
  const int kc0 = w, kc1 = w + 4, kc2 = w + 8;   // this wave's chunks (of 12)

  // issue tile-0 stage (latency hides under bias compute)
  {
    gld_lds16(K_lds + kc0 * 512, Khead + (size_t)(kc0 * 8 + rowb) * HDIM + srcc * 8);
    gld_lds16(K_lds + kc1 * 512, Khead + (size_t)(kc1 * 8 + rowb) * HDIM + srcc * 8);
    gld_lds16(K_lds + kc2 * 512, Khead + (size_t)(kc2 * 8 + rowb) * HDIM + srcc * 8);
    gld_lds16(V_lds + kc0 * 512, Vhead + kc0 * 512 + lane * 8);
    gld_lds16(V_lds + kc1 * 512, Vhead + kc1 * 512 + lane * 8);
    gld_lds16(V_lds + kc2 * 512, Vhead + kc2 * 512 + lane * 8);
  }
  // zero V pad keychunks 12,13 (disjoint from staged kc 0..11)
  *(uint4*)&V_lds[12 * 512 + t * 8] = uint4{0u, 0u, 0u, 0u};

  const s16x8 qf0 = *(const s16x8*)&Q_s[(w * 16 + p) * 72 + g * 8];
  const s16x8 qf1 = *(const s16x8*)&Q_s[(w * 16 + p) * 72 + 32 + g * 8];

  const int qh_lane = (l0 + lane) / 48;
#pragma unroll
  for (int i = 0; i < 12; ++i) {
    const int kh = w + 4 * i;
    const float* rrow = relh + (size_t)(qh_lane - kh + 47) * HDIM;
    float acc = 0.f;
#pragma unroll
    for (int c8 = 0; c8 < 8; ++c8) {
      s16x8 qv = *(const s16x8*)&Q_s[lane * 72 + c8 * 8];
      float4 ra = *(const float4*)&rrow[c8 * 8];
      float4 rb = *(const float4*)&rrow[c8 * 8 + 4];
      acc += b2f((unsigned short)qv[0]) * ra.x + b2f((unsigned short)qv[1]) * ra.y +
             b2f((unsigned short)qv[2]) * ra.z + b2f((unsigned short)qv[3]) * ra.w +
             b2f((unsigned short)qv[4]) * rb.x + b2f((unsigned short)qv[5]) * rb.y +
             b2f((unsigned short)qv[6]) * rb.z + b2f((unsigned short)qv[7]) * rb.w;
    }
    bh_t[kh * 64 + lane] = acc;
  }

  float bwreg[12];
  {
    const int qrow = w * 16 + p;
    const int qw_lane = (l0 + qrow) % 48;
#pragma unroll
    for (int mb = 0; mb < 3; ++mb)
#pragma unroll
      for (int jj = 0; jj < 4; ++jj) {
        const int j = 16 * mb + 4 * g + jj;
        const float* rrow = relw + (size_t)(qw_lane - j + 47) * HDIM;
        float acc = 0.f;
#pragma unroll
        for (int c8 = 0; c8 < 8; ++c8) {
          s16x8 qv = *(const s16x8*)&Q_s[qrow * 72 + c8 * 8];
          float4 ra = *(const float4*)&rrow[c8 * 8];
          float4 rb = *(const float4*)&rrow[c8 * 8 + 4];
          acc += b2f((unsigned short)qv[0]) * ra.x + b2f((unsigned short)qv[1]) * ra.y +
                 b2f((unsigned short)qv[2]) * ra.z + b2f((unsigned short)qv[3]) * ra.w +
                 b2f((unsigned short)qv[4]) * rb.x + b2f((unsigned short)qv[5]) * rb.y +
                 b2f((unsigned short)qv[6]) * rb.z + b2f((unsigned short)qv[7]) * rb.w;
        }
        bwreg[mb * 4 + jj] = acc;
      }
  }
  __syncthreads();  // Q dead; tile-0 loads drained; V pads visible

  // P zero pads (keys [48,64) per row) -- read only by this wave: no barrier needed
  {
    uint2 z = {0u, 0u};
    *(uint2*)&P_lds[(w * 16 + p) * 72 + 48 + 4 * g] = z;
  }

  float m = -3e38f, lsum = 0.f;
  f32x4 accO[4] = {};
  const int sw0 = g ^ (p & 7);
  const int sw1 = (g + 4) ^ (p & 7);
  unsigned short* const Pw = P_lds + w * 16 * 72;

#pragma unroll 1
  for (int kt = 0; kt < 24; ++kt) {
#pragma unroll 1
    for (int h = 0; h < 2; ++h) {
      // S^T = K . Q^T : D[key][q], col=p=q, row=4g+jj=key-in-16
      f32x4 st[3] = {};
      __builtin_amdgcn_s_setprio(1);
#pragma unroll
      for (int mb = 0; mb < 3; ++mb) {
        const int krow = (h * 48 + 16 * mb + p) * 64;
        s16x8 kf0 = *(const s16x8*)&K_lds[krow + sw0 * 8];
        s16x8 kf1 = *(const s16x8*)&K_lds[krow + sw1 * 8];
        st[mb] = __builtin_amdgcn_mfma_f32_16x16x32_bf16(kf0, qf0, st[mb], 0, 0, 0);
        st[mb] = __builtin_amdgcn_mfma_f32_16x16x32_bf16(kf1, qf1, st[mb], 0, 0, 0);
      }
      __builtin_amdgcn_s_setprio(0);

      // bias + online softmax (per lane: q-row = w*16+p, 12 keys)
      const float bhv = bh_t[(2 * kt + h) * 64 + w * 16 + p];
      float sv[12];
#pragma unroll
      for (int mb = 0; mb < 3; ++mb)
#pragma unroll
        for (int jj = 0; jj < 4; ++jj)
          sv[mb * 4 + jj] = st[mb][jj] * ATT_SCALE + bhv + bwreg[mb * 4 + jj];
      float tm = sv[0];
#pragma unroll
      for (int i = 1; i < 12; ++i) tm = fmaxf(tm, sv[i]);
      tm = fmaxf(tm, __shfl_xor(tm, 16, 64));
      tm = fmaxf(tm, __shfl_xor(tm, 32, 64));
      const float mn = fmaxf(m, tm);
      const float alpha = __expf(m - mn);
      m = mn;
      float pv[12], ps = 0.f;
#pragma unroll
      for (int i = 0; i < 12; ++i) { pv[i] = __expf(sv[i] - mn); ps += pv[i]; }
      ps += __shfl_xor(ps, 16, 64);
      ps += __shfl_xor(ps, 32, 64);
      lsum = lsum * alpha + ps;
#pragma unroll
      for (int db = 0; db < 4; ++db) accO[db] *= alpha;

      // P -> bf16 -> Pw rows (q=p), keys 16mb+4g+jj (pad zone pre-zeroed)
#pragma unroll
      for (int mb = 0; mb < 3; ++mb) {
        unsigned int lo = (unsigned int)f2b(pv[mb * 4 + 0]) | ((unsigned int)f2b(pv[mb * 4 + 1]) << 16);
        unsigned int hi = (unsigned int)f2b(pv[mb * 4 + 2]) | ((unsigned int)f2b(pv[mb * 4 + 3]) << 16);
        uint2 val = {lo, hi};
        *(uint2*)&Pw[p * 72 + 16 * mb + 4 * g] = val;
      }

      // PV: O^T[d][q] += V . P^T   (V subtiled: cell (kc,d) at (kc*64+d)*8)
      const s16x8 pf0 = *(const s16x8*)&Pw[p * 72 + g * 8];
      const s16x8 pf1 = *(const s16x8*)&Pw[p * 72 + 32 + g * 8];
      __builtin_amdgcn_s_setprio(1);
#pragma unroll
      for (int db = 0; db < 4; ++db) {
        const int drow = 16 * db + p;
        s16x8 vf0 = *(const s16x8*)&V_lds[((6 * h + g) * 64 + drow) * 8];
        s16x8 vf1 = *(const s16x8*)&V_lds[((6 * h + 4 + g) * 64 + drow) * 8];
        accO[db] = __builtin_amdgcn_mfma_f32_16x16x32_bf16(vf0, pf0, accO[db], 0, 0, 0);
        accO[db] = __builtin_amdgcn_mfma_f32_16x16x32_bf16(vf1, pf1, accO[db], 0, 0, 0);
      }
      __builtin_amdgcn_s_setprio(0);
    }

    __syncthreads();  // all waves done reading this tile
    if (kt < 23) {
      const int kb = (kt + 1) * 96;
      const int vb = (kt + 1) * 12;
      gld_lds16(K_lds + kc0 * 512, Khead + (size_t)(kb + kc0 * 8 + rowb) * HDIM + srcc * 8);
      gld_lds16(K_lds + kc1 * 512, Khead + (size_t)(kb + kc1 * 8 + rowb) * HDIM + srcc * 8);
      gld_lds16(K_lds + kc2 * 512, Khead + (size_t)(kb + kc2 * 8 + rowb) * HDIM + srcc * 8);
      gld_lds16(V_lds + kc0 * 512, Vhead + (vb + kc0) * 512 + lane * 8);
      gld_lds16(V_lds + kc1 * 512, Vhead + (vb + kc1) * 512 + lane * 8);
      gld_lds16(V_lds + kc2 * 512, Vhead + (vb + kc2) * 512 + lane * 8);
    }
    __syncthreads();  // next tile drained
  }

  // epilogue: lane's q-row = w*16+p; accO[db][jj] = O[q][16db+4g+jj]
  const float inv = 1.0f / lsum;
  unsigned short* orow = out + (size_t)(l0 + w * 16 + p) * CDIM + n * HDIM;
#pragma unroll
  for (int db = 0; db < 4; ++db) {
    unsigned int lo = (unsigned int)f2b(accO[db][0] * inv) | ((unsigned int)f2b(accO[db][1] * inv) << 16);
    unsigned int hi = (unsigned int)f2b(accO[db][2] * inv) | ((unsigned int)f2b(accO[db][3] * inv) << 16);
    uint2 val = {lo, hi};
    *(uint2*)&orow[16 * db + 4 * g] = val;
  }
}

// ---------------- launch ----------------
extern "C" void kernel_launch(void* const* d_in, const int* in_sizes, int n_in,
                              void* d_out, int out_size, void* d_ws, size_t ws_size,
                              hipStream_t stream) {
  const float* x     = (const float*)d_in[0];
  const float* ln1w  = (const float*)d_in[1];
  const float* ln1b  = (const float*)d_in[2];
  const float* qkvw  = (const float*)d_in[3];
  const float* qkvb  = (const float*)d_in[4];
  const float* relh  = (const float*)d_in[5];
  const float* relw  = (const float*)d_in[6];
  const float* projw = (const float*)d_in[7];
  const float* projb = (const float*)d_in[8];
  const float* ln2w  = (const float*)d_in[9];
  const float* ln2b  = (const float*)d_in[10];
  const float* fc1w  = (const float*)d_in[11];
  const float* fc1b  = (const float*)d_in[12];
  const float* fc2w  = (const float*)d_in[13];
  const float* fc2b  = (const float*)d_in[14];
  float* out = (float*)d_out;
  float* ws = (float*)d_ws;

  float* qkv = ws;                             // L*3C f32
  float* x1  = qkv + (size_t)LTOK * 3 * CDIM;  // L*C f32 (overlaid by Qb/Kb before proj)
  float* cs  = x1 + (size_t)LTOK * CDIM;
  float* sn  = cs + (size_t)LTOK * 32;
  unsigned short* h_bf    = (unsigned short*)(sn + (size_t)LTOK * 32);
  unsigned short* attn_bf = h_bf + (size_t)LTOK * CDIM;
  unsigned short* wq      = attn_bf + (size_t)LTOK * CDIM;
  unsigned short* wproj   = wq + (size_t)3 * CDIM * CDIM;
  unsigned short* wfc1    = wproj + (size_t)CDIM * CDIM;
  unsigned short* wfc2    = wfc1 + (size_t)4 * CDIM * CDIM;
  unsigned short* Qb      = (unsigned short*)x1;   // Qb+Kb fit x1 exactly
  unsigned short* Kb      = Qb + (size_t)NHEAD * LTOK * HDIM;
  unsigned short* Vb      = wq;                    // overlay: wq dead after qkv GEMM
  unsigned short* m1_bf   = (unsigned short*)qkv;  // overlay: qkv dead after prep

  f2b_kernel<<<(3 * CDIM * CDIM / 8 + 255) / 256, 256, 0, stream>>>(qkvw, wq, 3 * CDIM * CDIM);
  f2b_kernel<<<(CDIM * CDIM / 8 + 255) / 256, 256, 0, stream>>>(projw, wproj, CDIM * CDIM);
  f2b_kernel<<<(4 * CDIM * CDIM / 8 + 255) / 256, 256, 0, stream>>>(fc1w, wfc1, 4 * CDIM * CDIM);
  f2b_kernel<<<(4 * CDIM * CDIM / 8 + 255) / 256, 256, 0, stream>>>(fc2w, wfc2, 4 * CDIM * CDIM);

  ln_kernel<<<LTOK, 256, 0, stream>>>(x, ln1w, ln1b, h_bf);
  mfma_gemm<false, false, false><<<dim3(18, 18), 256, 0, stream>>>(
      h_bf, wq, qkvb, nullptr, qkv, LTOK, 3 * CDIM, CDIM);
  rope_cs_kernel<<<288, 256, 0, stream>>>(cs, sn);
  prep_kernel<<<dim3(36, 12), 256, 0, stream>>>(qkv, cs, sn, Qb, Kb, Vb);
  attn_mfma<<<dim3(36, 12), 256, 0, stream>>>(Qb, Kb, Vb, relh, relw, attn_bf);
  mfma_gemm<false, true, false><<<dim3(6, 18), 256, 0, stream>>>(
      attn_bf, wproj, projb, x, x1, LTOK, CDIM, CDIM);
  ln_kernel<<<LTOK, 256, 0, stream>>>(x1, ln2w, ln2b, h_bf);
  mfma_gemm<true, false, true><<<dim3(24, 18), 256, 0, stream>>>(
      h_bf, wfc1, fc1b, nullptr, m1_bf, LTOK, 4 * CDIM, CDIM);
  mfma_gemm<false, true, false><<<dim3(6, 18), 256, 0, stream>>>(
      m1_bf, wfc2, fc2b, x1, out, LTOK, CDIM, 4 * CDIM);
}

// Round 11
// 276.096 us; speedup vs baseline: 1.5773x; 1.0571x over previous
//
#include <hip/hip_runtime.h>
#include <math.h>

#define LTOK 2304
#define CDIM 768
#define NHEAD 12
#define HDIM 64
#define HS 48

typedef short s16x8 __attribute__((ext_vector_type(8)));   // 8 bf16 bits (4 VGPRs)
typedef float f32x4 __attribute__((ext_vector_type(4)));

__device__ __forceinline__ unsigned short f2b(float f) {
  __bf16 b = (__bf16)f;   // RNE
  return __builtin_bit_cast(unsigned short, b);
}
__device__ __forceinline__ float b2f(unsigned short u) {
  unsigned int x = ((unsigned int)u) << 16;
  return __builtin_bit_cast(float, x);
}

__device__ __forceinline__ void gld_lds16(void* lds, const void* g) {
  __builtin_amdgcn_global_load_lds(
      (const __attribute__((address_space(1))) unsigned int*)g,
      (__attribute__((address_space(3))) unsigned int*)lds, 16, 0, 0);
}

// ---------------- fp32 -> bf16 convert (n % 8 == 0) ----------------
__global__ __launch_bounds__(256) void f2b_kernel(const float* __restrict__ in,
                                                  unsigned short* __restrict__ out, int n) {
  const int i = (blockIdx.x * 256 + threadIdx.x) * 8;
  if (i + 8 > n) return;
  float4 v0 = *(const float4*)(in + i);
  float4 v1 = *(const float4*)(in + i + 4);
  alignas(16) unsigned short o[8] = {f2b(v0.x), f2b(v0.y), f2b(v0.z), f2b(v0.w),
                                     f2b(v1.x), f2b(v1.y), f2b(v1.z), f2b(v1.w)};
  *(uint4*)(out + i) = *(const uint4*)o;
}

// ---------------- LayerNorm: fp32 in, bf16 out ----------------
__global__ __launch_bounds__(256) void ln_kernel(const float* __restrict__ x,
                                                 const float* __restrict__ w,
                                                 const float* __restrict__ b,
                                                 unsigned short* __restrict__ out) {
  const int row = blockIdx.x;
  const int t = threadIdx.x;
  const float* xr = x + (size_t)row * CDIM;
  float v0 = xr[t], v1 = xr[t + 256], v2 = xr[t + 512];
  float s = v0 + v1 + v2;
  float ss = v0 * v0 + v1 * v1 + v2 * v2;
#pragma unroll
  for (int off = 32; off > 0; off >>= 1) {
    s += __shfl_down(s, off, 64);
    ss += __shfl_down(ss, off, 64);
  }
  __shared__ float rs[4], rss[4];
  if ((t & 63) == 0) { rs[t >> 6] = s; rss[t >> 6] = ss; }
  __syncthreads();
  float S = rs[0] + rs[1] + rs[2] + rs[3];
  float SS = rss[0] + rss[1] + rss[2] + rss[3];
  const float inv_c = 1.0f / (float)CDIM;
  float mu = S * inv_c;
  float var = SS * inv_c - mu * mu;
  float inv = rsqrtf(var + 1e-5f);
  unsigned short* orow = out + (size_t)row * CDIM;
  orow[t]       = f2b((v0 - mu) * inv * w[t]       + b[t]);
  orow[t + 256] = f2b((v1 - mu) * inv * w[t + 256] + b[t + 256]);
  orow[t + 512] = f2b((v2 - mu) * inv * w[t + 512] + b[t + 512]);
}

// ---------------- bf16 MFMA GEMM (m97 structure) ----------------
template <bool GELU, bool RES, bool OUTBF>
__global__ __launch_bounds__(256) void mfma_gemm(const unsigned short* __restrict__ A,
                                                 const unsigned short* __restrict__ B,
                                                 const float* __restrict__ bias,
                                                 const float* __restrict__ res,
                                                 void* __restrict__ Cout,
                                                 int M, int N, int K) {
  __shared__ unsigned short As[128 * 32];
  __shared__ unsigned short Bs[128 * 32];
  const int t = threadIdx.x;
  const int lane = t & 63;
  const int w = t >> 6;
  const int wm = w >> 1, wn = w & 1;
  const int bm = blockIdx.y * 128, bn = blockIdx.x * 128;

  f32x4 acc[4][4] = {};

  const int c0 = 2 * w, c1 = 2 * w + 1;
  const int srow = lane >> 2;
  const int skof = (lane & 3) * 8;
  const unsigned short* Abase = A + (size_t)bm * K + skof;
  const unsigned short* Bbase = B + (size_t)bn * K + skof;
  const int lr = lane & 15, lk = (lane >> 4) * 8, lg = lane >> 4;

  for (int k0 = 0; k0 < K; k0 += 32) {
    gld_lds16(As + c0 * 512, Abase + (size_t)(c0 * 16 + srow) * K + k0);
    gld_lds16(As + c1 * 512, Abase + (size_t)(c1 * 16 + srow) * K + k0);
    gld_lds16(Bs + c0 * 512, Bbase + (size_t)(c0 * 16 + srow) * K + k0);
    gld_lds16(Bs + c1 * 512, Bbase + (size_t)(c1 * 16 + srow) * K + k0);
    __syncthreads();
    s16x8 a[4], b[4];
#pragma unroll
    for (int m = 0; m < 4; ++m)
      a[m] = *(const s16x8*)&As[(wm * 64 + m * 16 + lr) * 32 + lk];
#pragma unroll
    for (int n = 0; n < 4; ++n)
      b[n] = *(const s16x8*)&Bs[(wn * 64 + n * 16 + lr) * 32 + lk];
#pragma unroll
    for (int m = 0; m < 4; ++m)
#pragma unroll
      for (int n = 0; n < 4; ++n)
        acc[m][n] = __builtin_amdgcn_mfma_f32_16x16x32_bf16(a[m], b[n], acc[m][n], 0, 0, 0);
    __syncthreads();
  }

#pragma unroll
  for (int n = 0; n < 4; ++n) {
    const int col = bn + wn * 64 + n * 16 + lr;
    const float bc = bias[col];
#pragma unroll
    for (int m = 0; m < 4; ++m) {
#pragma unroll
      for (int j = 0; j < 4; ++j) {
        const int row = bm + wm * 64 + m * 16 + lg * 4 + j;
        float v = acc[m][n][j] + bc;
        if (GELU) v = 0.5f * v * (1.0f + erff(v * 0.70710678118654752f));
        if (RES) v += res[(size_t)row * N + col];
        if (OUTBF) ((unsigned short*)Cout)[(size_t)row * N + col] = f2b(v);
        else       ((float*)Cout)[(size_t)row * N + col] = v;
      }
    }
  }
}

// ---------------- RoPE cos/sin tables: [L][32] ----------------
__global__ __launch_bounds__(256) void rope_cs_kernel(float* __restrict__ cs,
                                                      float* __restrict__ sn) {
  const int idx = blockIdx.x * 256 + threadIdx.x;  // < 2304*32
  const int l = idx >> 5;
  const int i = idx & 31;
  const int j = i & 15;
  const float f = __expf(-(float)j * 0.57564627324851142f);
  const float coord = (i < 16) ? (float)(l % HS) : (float)(l / HS);
  const float ang = coord * f;
  cs[idx] = cosf(ang);
  sn[idx] = sinf(ang);
}

// ---------------- prep: qkv -> Qb (x0.125, RoPE), Kb (RoPE), Vb subtiled -----------
// Qb pre-scaled by ATT_SCALE=0.125 (bias accumulators in attn multiply by 8).
// Vb layout: [NH][L/8 keychunks][64 d][8 keys]
// grid (36, 12), 256 threads
__global__ __launch_bounds__(256) void prep_kernel(const float* __restrict__ qkv,
                                                   const float* __restrict__ cs,
                                                   const float* __restrict__ sn,
                                                   unsigned short* __restrict__ Qb,
                                                   unsigned short* __restrict__ Kb,
                                                   unsigned short* __restrict__ Vb) {
  __shared__ unsigned short Vs[64 * 72];
  const int t = threadIdx.x;
  const int l0 = blockIdx.x * 64, n = blockIdx.y;
  const int r = t >> 2, c = t & 3;
  const int l = l0 + r;
  const float* base = qkv + (size_t)l * (3 * CDIM) + n * HDIM + c * 16;
#pragma unroll
  for (int pq = 0; pq < 2; ++pq) {
    const float* src = base + pq * CDIM;
    const float qs = pq ? 1.0f : 0.125f;
    alignas(16) unsigned short o[16];
#pragma unroll
    for (int i = 0; i < 4; ++i) {
      float4 v = *(const float4*)(src + i * 4);
      const int pr = c * 8 + i * 2;
      const float c0 = cs[l * 32 + pr],     s0 = sn[l * 32 + pr];
      const float c1 = cs[l * 32 + pr + 1], s1 = sn[l * 32 + pr + 1];
      o[i * 4 + 0] = f2b((v.x * c0 - v.y * s0) * qs);
      o[i * 4 + 1] = f2b((v.x * s0 + v.y * c0) * qs);
      o[i * 4 + 2] = f2b((v.z * c1 - v.w * s1) * qs);
      o[i * 4 + 3] = f2b((v.z * s1 + v.w * c1) * qs);
    }
    unsigned short* dst = (pq ? Kb : Qb) + ((size_t)n * LTOK + l) * HDIM + c * 16;
    *(uint4*)dst = *(const uint4*)o;
    *(uint4*)(dst + 8) = *(const uint4*)(o + 8);
  }
  // V transpose via LDS, then write subtiled [kc][d][8]
  {
    const float* vsrc = base + 2 * CDIM;
    alignas(16) unsigned short vo[16];
#pragma unroll
    for (int i = 0; i < 4; ++i) {
      float4 v = *(const float4*)(vsrc + i * 4);
      vo[i * 4 + 0] = f2b(v.x); vo[i * 4 + 1] = f2b(v.y);
      vo[i * 4 + 2] = f2b(v.z); vo[i * 4 + 3] = f2b(v.w);
    }
    *(uint4*)&Vs[r * 72 + c * 16] = *(const uint4*)vo;
    *(uint4*)&Vs[r * 72 + c * 16 + 8] = *(const uint4*)(vo + 8);
  }
  __syncthreads();
  {
    const int d = t >> 2, kc16 = (t & 3) * 16;
    alignas(16) unsigned short o[16];
#pragma unroll
    for (int i = 0; i < 16; ++i) o[i] = Vs[(kc16 + i) * 72 + d];
    const int kb = (l0 + kc16) >> 3;  // global key-chunk
    unsigned short* dst0 = Vb + ((size_t)(n * (LTOK / 8) + kb) * 64 + d) * 8;
    unsigned short* dst1 = Vb + ((size_t)(n * (LTOK / 8) + kb + 1) * 64 + d) * 8;
    *(uint4*)dst0 = *(const uint4*)o;
    *(uint4*)dst1 = *(const uint4*)(o + 8);
  }
}

// ---------------- MFMA flash attention: KVB=96, DOUBLE-buffered, fixed-shift SM ----
// grid (36, 12), 256 threads = 4 waves x 16 q-rows.
// Per iter: { stage kt+1 -> other buffer (gld_lds) ; compute both 48-key halves of
//             current buffer ; ONE barrier }.  Buffer select = runtime LDS offset
// (kt&1)*CONST -- not a loop-carried pointer (R8 spill) -- and #pragma unroll 1.
// Softmax: FIXED shift 8 (exact: softmax is shift-invariant; |s|<~15 << 88), which
// deletes the running max, 4 shfl_xor, alpha-exp and accO rescales per half-step.
// lsum is per-lane; cross-lane (g) reduce once in epilogue.
// Q pre-scaled 0.125 in prep; bias accs here x8.
// LDS map (bytes):
//   K   @     0 (2 x 12288)  96 rows x 64 shorts per buf, chunk-XOR swizzle (src)
//   V   @ 24576 (2 x 14336)  subtiled [14 kc][64 d][8]; kc 12,13 = zero pads per buf
//   P   @ 53248 ( 9216)  4 waves x [16 q][72]
//   bh  @ 62464 (12288)  [48 kh-tiles][64 q] f32
//   Q_s overlays P @ 53248 (9216; dead after prologue)      total 74752 -> 2 blk/CU
__global__ __launch_bounds__(256) void attn_mfma(const unsigned short* __restrict__ Qb,
                                                 const unsigned short* __restrict__ Kb,
                                                 const unsigned short* __restrict__ Vb,
                                                 const float* __restrict__ relh,
                                                 const float* __restrict__ relw,
                                                 unsigned short* __restrict__ out) {
  __shared__ __align__(16) unsigned char smem[74752];
  unsigned short* const K_lds = (unsigned short*)(smem);           // +b*6144 shorts
  unsigned short* const V_lds = (unsigned short*)(smem + 24576);   // +b*7168 shorts
  unsigned short* const P_lds = (unsigned short*)(smem + 53248);
  float* const bh_t = (float*)(smem + 62464);
  unsigned short* const Q_s = (unsigned short*)(smem + 53248);     // overlays P

  const int t = threadIdx.x;
  const int lane = t & 63, w = t >> 6;
  const int p = lane & 15, g = lane >> 4;
  const int l0 = blockIdx.x * 64, n = blockIdx.y;

  const unsigned short* Khead = Kb + (size_t)n * LTOK * HDIM;
  const unsigned short* Vhead = Vb + (size_t)n * (LTOK / 8) * 64 * 8;

  // ---- stage Q into padded Q_s (overlays P) ----
  {
    const int r = t >> 2, c = t & 3;
    const unsigned short* src = Qb + ((size_t)n * LTOK + l0 + r) * HDIM + c * 16;
    uint4 v0 = *(const uint4*)src;
    uint4 v1 = *(const uint4*)(src + 8);
    *(uint4*)&Q_s[r * 72 + c * 16] = v0;
    *(uint4*)&Q_s[r * 72 + c * 16 + 8] = v1;
  }
  __syncthreads();

  // ---- staging geometry ----
  const int rowb = lane >> 3;
  const int srcc = (lane & 7) ^ rowb;
  const int kc0 = w, kc1 = w + 4, kc2 = w + 8;   // this wave's chunks (of 12)

  // issue tile-0 stage into buffer 0 (latency hides under bias compute)
  {
    gld_lds16(K_lds + kc0 * 512, Khead + (size_t)(kc0 * 8 + rowb) * HDIM + srcc * 8);
    gld_lds16(K_lds + kc1 * 512, Khead + (size_t)(kc1 * 8 + rowb) * HDIM + srcc * 8);
    gld_lds16(K_lds + kc2 * 512, Khead + (size_t)(kc2 * 8 + rowb) * HDIM + srcc * 8);
    gld_lds16(V_lds + kc0 * 512, Vhead + kc0 * 512 + lane * 8);
    gld_lds16(V_lds + kc1 * 512, Vhead + kc1 * 512 + lane * 8);
    gld_lds16(V_lds + kc2 * 512, Vhead + kc2 * 512 + lane * 8);
  }
  // zero V pad keychunks 12,13 of BOTH buffers (disjoint from staged kc 0..11)
  if (t < 128) *(uint4*)&V_lds[6144 + t * 8] = uint4{0u, 0u, 0u, 0u};
  else         *(uint4*)&V_lds[7168 + 6144 + (t - 128) * 8] = uint4{0u, 0u, 0u, 0u};

  const s16x8 qf0 = *(const s16x8*)&Q_s[(w * 16 + p) * 72 + g * 8];
  const s16x8 qf1 = *(const s16x8*)&Q_s[(w * 16 + p) * 72 + 32 + g * 8];

  const int qh_lane = (l0 + lane) / 48;
#pragma unroll
  for (int i = 0; i < 12; ++i) {
    const int kh = w + 4 * i;
    const float* rrow = relh + (size_t)(qh_lane - kh + 47) * HDIM;
    float acc = 0.f;
#pragma unroll
    for (int c8 = 0; c8 < 8; ++c8) {
      s16x8 qv = *(const s16x8*)&Q_s[lane * 72 + c8 * 8];
      float4 ra = *(const float4*)&rrow[c8 * 8];
      float4 rb = *(const float4*)&rrow[c8 * 8 + 4];
      acc += b2f((unsigned short)qv[0]) * ra.x + b2f((unsigned short)qv[1]) * ra.y +
             b2f((unsigned short)qv[2]) * ra.z + b2f((unsigned short)qv[3]) * ra.w +
             b2f((unsigned short)qv[4]) * rb.x + b2f((unsigned short)qv[5]) * rb.y +
             b2f((unsigned short)qv[6]) * rb.z + b2f((unsigned short)qv[7]) * rb.w;
    }
    bh_t[kh * 64 + lane] = acc * 8.0f;   // undo Q prescale (bias is unscaled in ref)
  }

  float bwreg[12];
  {
    const int qrow = w * 16 + p;
    const int qw_lane = (l0 + qrow) % 48;
#pragma unroll
    for (int mb = 0; mb < 3; ++mb)
#pragma unroll
      for (int jj = 0; jj < 4; ++jj) {
        const int j = 16 * mb + 4 * g + jj;
        const float* rrow = relw + (size_t)(qw_lane - j + 47) * HDIM;
        float acc = 0.f;
#pragma unroll
        for (int c8 = 0; c8 < 8; ++c8) {
          s16x8 qv = *(const s16x8*)&Q_s[qrow * 72 + c8 * 8];
          float4 ra = *(const float4*)&rrow[c8 * 8];
          float4 rb = *(const float4*)&rrow[c8 * 8 + 4];
          acc += b2f((unsigned short)qv[0]) * ra.x + b2f((unsigned short)qv[1]) * ra.y +
                 b2f((unsigned short)qv[2]) * ra.z + b2f((unsigned short)qv[3]) * ra.w +
                 b2f((unsigned short)qv[4]) * rb.x + b2f((unsigned short)qv[5]) * rb.y +
                 b2f((unsigned short)qv[6]) * rb.z + b2f((unsigned short)qv[7]) * rb.w;
        }
        bwreg[mb * 4 + jj] = acc * 8.0f;
      }
  }
  __syncthreads();  // Q dead; tile-0 loads drained; V pads visible

  // P zero pads (keys [48,64) per row) -- read only by this wave: no barrier needed
  {
    uint2 z = {0u, 0u};
    *(uint2*)&P_lds[(w * 16 + p) * 72 + 48 + 4 * g] = z;
  }

  float lsum = 0.f;
  f32x4 accO[4] = {};
  const int sw0 = g ^ (p & 7);
  const int sw1 = (g + 4) ^ (p & 7);
  unsigned short* const Pw = P_lds + w * 16 * 72;

#pragma unroll 1
  for (int kt = 0; kt < 24; ++kt) {
    const int ko = (kt & 1) * 6144;   // current K buffer offset (shorts)
    const int vo = (kt & 1) * 7168;   // current V buffer offset (shorts)
    // stage tile kt+1 into the OTHER buffer; drained by the end-of-iter barrier,
    // i.e. its latency overlaps this whole iteration's compute.
    if (kt < 23) {
      const int nko = 6144 - ko, nvo = 7168 - vo;
      const int kb = (kt + 1) * 96;
      const int vb = (kt + 1) * 12;
      gld_lds16(K_lds + nko + kc0 * 512, Khead + (size_t)(kb + kc0 * 8 + rowb) * HDIM + srcc * 8);
      gld_lds16(K_lds + nko + kc1 * 512, Khead + (size_t)(kb + kc1 * 8 + rowb) * HDIM + srcc * 8);
      gld_lds16(K_lds + nko + kc2 * 512, Khead + (size_t)(kb + kc2 * 8 + rowb) * HDIM + srcc * 8);
      gld_lds16(V_lds + nvo + kc0 * 512, Vhead + (vb + kc0) * 512 + lane * 8);
      gld_lds16(V_lds + nvo + kc1 * 512, Vhead + (vb + kc1) * 512 + lane * 8);
      gld_lds16(V_lds + nvo + kc2 * 512, Vhead + (vb + kc2) * 512 + lane * 8);
    }

#pragma unroll 1
    for (int h = 0; h < 2; ++h) {
      // S^T = K . Q^T : D[key][q], col=p=q, row=4g+jj=key-in-16
      f32x4 st[3] = {};
      __builtin_amdgcn_s_setprio(1);
#pragma unroll
      for (int mb = 0; mb < 3; ++mb) {
        const int krow = ko + (h * 48 + 16 * mb + p) * 64;
        s16x8 kf0 = *(const s16x8*)&K_lds[krow + sw0 * 8];
        s16x8 kf1 = *(const s16x8*)&K_lds[krow + sw1 * 8];
        st[mb] = __builtin_amdgcn_mfma_f32_16x16x32_bf16(kf0, qf0, st[mb], 0, 0, 0);
        st[mb] = __builtin_amdgcn_mfma_f32_16x16x32_bf16(kf1, qf1, st[mb], 0, 0, 0);
      }
      __builtin_amdgcn_s_setprio(0);

      // fixed-shift softmax: P = exp(s + bias - 8); no running max, no rescale
      const float bhv = bh_t[(2 * kt + h) * 64 + w * 16 + p] - 8.0f;
      float pv[12], ps = 0.f;
#pragma unroll
      for (int mb = 0; mb < 3; ++mb)
#pragma unroll
        for (int jj = 0; jj < 4; ++jj) {
          const float sv = st[mb][jj] + bhv + bwreg[mb * 4 + jj];
          pv[mb * 4 + jj] = __expf(sv);
          ps += pv[mb * 4 + jj];
        }
      lsum += ps;

      // P -> bf16 -> Pw rows (q=p), keys 16mb+4g+jj (pad zone pre-zeroed)
#pragma unroll
      for (int mb = 0; mb < 3; ++mb) {
        unsigned int lo = (unsigned int)f2b(pv[mb * 4 + 0]) | ((unsigned int)f2b(pv[mb * 4 + 1]) << 16);
        unsigned int hi = (unsigned int)f2b(pv[mb * 4 + 2]) | ((unsigned int)f2b(pv[mb * 4 + 3]) << 16);
        uint2 val = {lo, hi};
        *(uint2*)&Pw[p * 72 + 16 * mb + 4 * g] = val;
      }

      // PV: O^T[d][q] += V . P^T   (V subtiled: cell (kc,d) at vo+(kc*64+d)*8)
      const s16x8 pf0 = *(const s16x8*)&Pw[p * 72 + g * 8];
      const s16x8 pf1 = *(const s16x8*)&Pw[p * 72 + 32 + g * 8];
      __builtin_amdgcn_s_setprio(1);
#pragma unroll
      for (int db = 0; db < 4; ++db) {
        const int drow = 16 * db + p;
        s16x8 vf0 = *(const s16x8*)&V_lds[vo + ((6 * h + g) * 64 + drow) * 8];
        s16x8 vf1 = *(const s16x8*)&V_lds[vo + ((6 * h + 4 + g) * 64 + drow) * 8];
        accO[db] = __builtin_amdgcn_mfma_f32_16x16x32_bf16(vf0, pf0, accO[db], 0, 0, 0);
        accO[db] = __builtin_amdgcn_mfma_f32_16x16x32_bf16(vf1, pf1, accO[db], 0, 0, 0);
      }
      __builtin_amdgcn_s_setprio(0);
    }

    __syncthreads();  // all waves done reading current buffers; next-tile stage drained
  }

  // epilogue: reduce lsum across the 4 g-lanes of each q-row, then write O
  float ls = lsum + __shfl_xor(lsum, 16, 64);
  ls += __shfl_xor(ls, 32, 64);
  const float inv = 1.0f / ls;
  unsigned short* orow = out + (size_t)(l0 + w * 16 + p) * CDIM + n * HDIM;
#pragma unroll
  for (int db = 0; db < 4; ++db) {
    unsigned int lo = (unsigned int)f2b(accO[db][0] * inv) | ((unsigned int)f2b(accO[db][1] * inv) << 16);
    unsigned int hi = (unsigned int)f2b(accO[db][2] * inv) | ((unsigned int)f2b(accO[db][3] * inv) << 16);
    uint2 val = {lo, hi};
    *(uint2*)&orow[16 * db + 4 * g] = val;
  }
}

// ---------------- launch ----------------
extern "C" void kernel_launch(void* const* d_in, const int* in_sizes, int n_in,
                              void* d_out, int out_size, void* d_ws, size_t ws_size,
                              hipStream_t stream) {
  const float* x     = (const float*)d_in[0];
  const float* ln1w  = (const float*)d_in[1];
  const float* ln1b  = (const float*)d_in[2];
  const float* qkvw  = (const float*)d_in[3];
  const float* qkvb  = (const float*)d_in[4];
  const float* relh  = (const float*)d_in[5];
  const float* relw  = (const float*)d_in[6];
  const float* projw = (const float*)d_in[7];
  const float* projb = (const float*)d_in[8];
  const float* ln2w  = (const float*)d_in[9];
  const float* ln2b  = (const float*)d_in[10];
  const float* fc1w  = (const float*)d_in[11];
  const float* fc1b  = (const float*)d_in[12];
  const float* fc2w  = (const float*)d_in[13];
  const float* fc2b  = (const float*)d_in[14];
  float* out = (float*)d_out;
  float* ws = (float*)d_ws;

  float* qkv = ws;                             // L*3C f32
  float* x1  = qkv + (size_t)LTOK * 3 * CDIM;  // L*C f32 (overlaid by Qb/Kb before proj)
  float* cs  = x1 + (size_t)LTOK * CDIM;
  float* sn  = cs + (size_t)LTOK * 32;
  unsigned short* h_bf    = (unsigned short*)(sn + (size_t)LTOK * 32);
  unsigned short* attn_bf = h_bf + (size_t)LTOK * CDIM;
  unsigned short* wq      = attn_bf + (size_t)LTOK * CDIM;
  unsigned short* wproj   = wq + (size_t)3 * CDIM * CDIM;
  unsigned short* wfc1    = wproj + (size_t)CDIM * CDIM;
  unsigned short* wfc2    = wfc1 + (size_t)4 * CDIM * CDIM;
  unsigned short* Qb      = (unsigned short*)x1;   // Qb+Kb fit x1 exactly
  unsigned short* Kb      = Qb + (size_t)NHEAD * LTOK * HDIM;
  unsigned short* Vb      = wq;                    // overlay: wq dead after qkv GEMM
  unsigned short* m1_bf   = (unsigned short*)qkv;  // overlay: qkv dead after prep

  f2b_kernel<<<(3 * CDIM * CDIM / 8 + 255) / 256, 256, 0, stream>>>(qkvw, wq, 3 * CDIM * CDIM);
  f2b_kernel<<<(CDIM * CDIM / 8 + 255) / 256, 256, 0, stream>>>(projw, wproj, CDIM * CDIM);
  f2b_kernel<<<(4 * CDIM * CDIM / 8 + 255) / 256, 256, 0, stream>>>(fc1w, wfc1, 4 * CDIM * CDIM);
  f2b_kernel<<<(4 * CDIM * CDIM / 8 + 255) / 256, 256, 0, stream>>>(fc2w, wfc2, 4 * CDIM * CDIM);

  ln_kernel<<<LTOK, 256, 0, stream>>>(x, ln1w, ln1b, h_bf);
  mfma_gemm<false, false, false><<<dim3(18, 18), 256, 0, stream>>>(
      h_bf, wq, qkvb, nullptr, qkv, LTOK, 3 * CDIM, CDIM);
  rope_cs_kernel<<<288, 256, 0, stream>>>(cs, sn);
  prep_kernel<<<dim3(36, 12), 256, 0, stream>>>(qkv, cs, sn, Qb, Kb, Vb);
  attn_mfma<<<dim3(36, 12), 256, 0, stream>>>(Qb, Kb, Vb, relh, relw, attn_bf);
  mfma_gemm<false, true, false><<<dim3(6, 18), 256, 0, stream>>>(
      attn_bf, wproj, projb, x, x1, LTOK, CDIM, CDIM);
  ln_kernel<<<LTOK, 256, 0, stream>>>(x1, ln2w, ln2b, h_bf);
  mfma_gemm<true, false, true><<<dim3(24, 18), 256, 0, stream>>>(
      h_bf, wfc1, fc1b, nullptr, m1_bf, LTOK, 4 * CDIM, CDIM);
  mfma_gemm<false, true, false><<<dim3(6, 18), 256, 0, stream>>>(
      m1_bf, wfc2, fc2b, x1, out, LTOK, CDIM, 4 * CDIM);
}